// Round 10
// baseline (394.411 us; speedup 1.0000x reference)
//
#include <hip/hip_runtime.h>
#include <hip/hip_bf16.h>
#include <math.h>
#include <stddef.h>

#define NN 8192
#define NEG_SLOPE 0.2f

typedef _Float16 h8 __attribute__((ext_vector_type(8)));
typedef __attribute__((ext_vector_type(4))) float f32x4;

__device__ __forceinline__ float lrelu(float x) { return x > 0.f ? x : NEG_SLOPE * x; }
__device__ __forceinline__ float sigf(float x) { return 1.f / (1.f + __expf(-x)); }

__device__ __forceinline__ unsigned short f16b(float x) {
    _Float16 h = (_Float16)x;
    unsigned short u;
    __builtin_memcpy(&u, &h, 2);
    return u;
}
__device__ __forceinline__ float f16f(unsigned short u) {
    _Float16 h;
    __builtin_memcpy(&h, &u, 2);
    return (float)h;
}
__device__ __forceinline__ void splith(float x, unsigned short& hu, unsigned short& lu) {
    _Float16 h = (_Float16)x;
    float hf = (float)h;
    _Float16 l = (_Float16)(x - hf);
    __builtin_memcpy(&hu, &h, 2);
    __builtin_memcpy(&lu, &l, 2);
}
__device__ __forceinline__ float2 unpkh(unsigned int v) {
    float2 r;
    r.x = f16f((unsigned short)(v & 0xffffu));
    r.y = f16f((unsigned short)(v >> 16));
    return r;
}
__device__ __forceinline__ unsigned int packh(float a, float b) {
    return (unsigned int)f16b(a) | ((unsigned int)f16b(b) << 16);
}

// async global->LDS, 16B per lane; lds base must be wave-uniform
__device__ __forceinline__ void gll16(const unsigned short* g, unsigned short* l) {
    __builtin_amdgcn_global_load_lds(
        (const __attribute__((address_space(1))) unsigned int*)g,
        (__attribute__((address_space(3))) unsigned int*)l, 16, 0, 0);
}

// ---------------- CSR build ----------------
__global__ void k_zero(int* __restrict__ p, int n) {
    int i = blockIdx.x * blockDim.x + threadIdx.x;
    if (i < n) p[i] = 0;
}
__global__ void k_count(const int* __restrict__ dst, int* __restrict__ cnt, int E) {
    int i = blockIdx.x * blockDim.x + threadIdx.x;
    if (i < E) atomicAdd(&cnt[dst[i]], 1);
}
__global__ void k_dinv(const int* __restrict__ cnt, float* __restrict__ dinv) {
    int i = blockIdx.x * blockDim.x + threadIdx.x;
    if (i < NN) dinv[i] = rsqrtf((float)(cnt[i] + 1));
}
__global__ void k_scan(const int* __restrict__ cnt, int* __restrict__ row_ptr) {
    __shared__ int part[1024];
    int t = threadIdx.x;
    int base = t * 8;
    int loc[8];
    int s = 0;
    #pragma unroll
    for (int j = 0; j < 8; ++j) { loc[j] = s; s += cnt[base + j]; }
    part[t] = s;
    __syncthreads();
    for (int off = 1; off < 1024; off <<= 1) {
        int v = (t >= off) ? part[t - off] : 0;
        __syncthreads();
        part[t] += v;
        __syncthreads();
    }
    int pre = (t == 0) ? 0 : part[t - 1];
    #pragma unroll
    for (int j = 0; j < 8; ++j) row_ptr[base + j] = pre + loc[j];
    if (t == 1023) row_ptr[NN] = part[1023];
}
__global__ void k_fill(const int* __restrict__ src, const int* __restrict__ dst,
                       const int* __restrict__ row_ptr, int* __restrict__ cursor,
                       int* __restrict__ csr_src, int E) {
    int i = blockIdx.x * blockDim.x + threadIdx.x;
    if (i < E) {
        int d = dst[i];
        csr_src[row_ptr[d] + atomicAdd(&cursor[d], 1)] = src[i];
    }
}

// ---------------- x fp32 -> fp16 ----------------
__global__ void k_cvt_x(const float* __restrict__ x, unsigned short* __restrict__ xh) {
    int i = blockIdx.x * 256 + threadIdx.x;     // over NN*512/4
    int m = i >> 7, k4 = (i & 127) * 4;
    float4 v = *(const float4*)(x + (size_t)m * 512 + k4);
    ushort4 o;
    o.x = f16b(v.x); o.y = f16b(v.y); o.z = f16b(v.z); o.w = f16b(v.w);
    *(ushort4*)&xh[(size_t)m * 512 + k4] = o;
}

// W[z] [K,N] fp32 -> Wt fp16 rows (noff + z*noff_z + n) of length K
__global__ void k_wT(const float* __restrict__ W, unsigned short* __restrict__ Wt,
                     int K, int N, size_t wt_z_stride, int noff, int noff_z) {
    int b = blockIdx.z;
    W += (size_t)b * K * N;
    Wt += (size_t)b * wt_z_stride;
    int rowbase = noff + b * noff_z;
    int k0 = blockIdx.x * 32, n0 = blockIdx.y * 32;
    __shared__ float tl[32][33];
    int tid = threadIdx.x;
    int r = tid >> 5, cc = tid & 31;
    #pragma unroll
    for (int c = 0; c < 4; ++c)
        tl[r + c * 8][cc] = W[(size_t)(k0 + r + c * 8) * N + n0 + cc];
    __syncthreads();
    #pragma unroll
    for (int c = 0; c < 4; ++c) {
        int n = r + c * 8, k = cc;
        Wt[(size_t)(rowbase + n0 + n) * K + k0 + k] = f16b(tl[k][n]);
    }
}

// ---------------- fp16 MFMA GEMM, global_load_lds staging ----------------
template <int ROWS>
__device__ __forceinline__ void stage(const unsigned short* __restrict__ gbase, int lda,
                                      unsigned short* lds, int wid, int lane) {
    #pragma unroll
    for (int c = 0; c < ROWS / 32; ++c) {
        int chunk = c * 4 + wid;                // 1KB chunks
        int row = chunk * 8 + (lane >> 3);
        int g = (lane & 7) ^ (row & 7);
        gll16(gbase + (size_t)row * lda + g * 8, lds + chunk * 512);
    }
}
__device__ __forceinline__ h8 fragrh(const unsigned short* lds, int row, int kg) {
    return *(const h8*)(lds + row * 64 + ((kg ^ (row & 7)) * 8));
}

// TERMS: 1 = Ah*Bh; 2 = (Ah+Al)*Bh; 3 = Ah*Bh+Al*Bh+Ah*Bl
template <int TERMS, int EPI>   // EPI: 0 fp32, 1 fp32+sigmoid(nt), 2 fp16
__global__ __launch_bounds__(256) void k_gemm2(
    const unsigned short* __restrict__ A2, size_t azs, int lda,
    const unsigned short* __restrict__ B2, size_t bzs, int ldb,
    void* __restrict__ Cv, size_t czs, int ldc, int K) {
    __shared__ __align__(16) unsigned short sAh[128 * 64];
    __shared__ __align__(16) unsigned short sBh[64 * 64];
    __shared__ __align__(16) unsigned short sAl[(TERMS >= 2) ? 128 * 64 : 8];
    __shared__ __align__(16) unsigned short sBl[(TERMS >= 3) ? 64 * 64 : 8];
    const int tid = threadIdx.x;
    const int wid = tid >> 6, lane = tid & 63;
    const int wr = wid >> 1, wc = wid & 1;
    const int lr = lane & 15, lg = lane >> 4;
    const int m0 = blockIdx.x * 128, n0 = blockIdx.y * 64;
    const int z = blockIdx.z;
    A2 += (size_t)z * azs;
    B2 += (size_t)z * bzs;

    const f32x4 zero4 = {0.f, 0.f, 0.f, 0.f};
    f32x4 acc[4][2];
    #pragma unroll
    for (int m = 0; m < 4; ++m)
        #pragma unroll
        for (int n = 0; n < 2; ++n) acc[m][n] = zero4;

    for (int k0 = 0; k0 < K; k0 += 64) {
        stage<128>(A2 + (size_t)m0 * lda + k0, lda, sAh, wid, lane);
        stage<64> (B2 + (size_t)n0 * ldb + k0, ldb, sBh, wid, lane);
        if (TERMS >= 2) stage<128>(A2 + (size_t)m0 * lda + K + k0, lda, sAl, wid, lane);
        if (TERMS >= 3) stage<64> (B2 + (size_t)n0 * ldb + K + k0, ldb, sBl, wid, lane);
        __syncthreads();
        #pragma unroll
        for (int ks = 0; ks < 2; ++ks) {
            const int kg = ks * 4 + lg;
            h8 ah[4], al[4], bh[2], bl[2];
            #pragma unroll
            for (int m = 0; m < 4; ++m) {
                int row = wr * 64 + m * 16 + lr;
                ah[m] = fragrh(sAh, row, kg);
                if (TERMS >= 2) al[m] = fragrh(sAl, row, kg);
            }
            #pragma unroll
            for (int n = 0; n < 2; ++n) {
                int row = wc * 32 + n * 16 + lr;
                bh[n] = fragrh(sBh, row, kg);
                if (TERMS >= 3) bl[n] = fragrh(sBl, row, kg);
            }
            #pragma unroll
            for (int m = 0; m < 4; ++m)
                #pragma unroll
                for (int n = 0; n < 2; ++n) {
                    acc[m][n] = __builtin_amdgcn_mfma_f32_16x16x32_f16(ah[m], bh[n], acc[m][n], 0, 0, 0);
                    if (TERMS >= 2)
                        acc[m][n] = __builtin_amdgcn_mfma_f32_16x16x32_f16(al[m], bh[n], acc[m][n], 0, 0, 0);
                    if (TERMS >= 3)
                        acc[m][n] = __builtin_amdgcn_mfma_f32_16x16x32_f16(ah[m], bl[n], acc[m][n], 0, 0, 0);
                }
        }
        __syncthreads();
    }
    #pragma unroll
    for (int m = 0; m < 4; ++m)
        #pragma unroll
        for (int n = 0; n < 2; ++n)
            #pragma unroll
            for (int j = 0; j < 4; ++j) {
                int row = m0 + wr * 64 + m * 16 + lg * 4 + j;
                int col = n0 + wc * 32 + n * 16 + lr;
                float o = acc[m][n][j];
                if (EPI == 1) {
                    float* cp = (float*)Cv + (size_t)z * czs + (size_t)row * ldc + col;
                    __builtin_nontemporal_store(sigf(o), cp);
                } else if (EPI == 2) {
                    ((unsigned short*)Cv + (size_t)z * czs)[(size_t)row * ldc + col] = f16b(o);
                } else {
                    ((float*)Cv + (size_t)z * czs)[(size_t)row * ldc + col] = o;
                }
            }
}

// ---------------- GCN layer1 aggregate: h = relu(Agg(xwh)+b1), 64 thr x uint2 --------
__global__ void k_gcn_a1(const uint2* __restrict__ xw2, const float* __restrict__ dinv,
                         const int* __restrict__ rp, const int* __restrict__ cs,
                         const float* __restrict__ b1, uint2* __restrict__ hb2) {
    int d = blockIdx.x;
    int t = threadIdx.x;                         // 64 uint2 cols (256 fp)
    float dd = dinv[d];
    uint2 sv = xw2[(size_t)d * 64 + t];
    float2 s0 = unpkh(sv.x), s1 = unpkh(sv.y);
    float a0 = dd * s0.x, a1 = dd * s0.y, a2 = dd * s1.x, a3 = dd * s1.y;
    int e0 = rp[d], e1 = rp[d + 1];
    int j = e0;
    for (; j + 4 <= e1; j += 4) {
        int i0 = cs[j], i1 = cs[j + 1], i2 = cs[j + 2], i3 = cs[j + 3];
        float w0 = dinv[i0], w1 = dinv[i1], w2 = dinv[i2], w3 = dinv[i3];
        uint2 v0 = xw2[(size_t)i0 * 64 + t];
        uint2 v1 = xw2[(size_t)i1 * 64 + t];
        uint2 v2 = xw2[(size_t)i2 * 64 + t];
        uint2 v3 = xw2[(size_t)i3 * 64 + t];
        float2 p;
        p = unpkh(v0.x); a0 += w0 * p.x; a1 += w0 * p.y;
        p = unpkh(v0.y); a2 += w0 * p.x; a3 += w0 * p.y;
        p = unpkh(v1.x); a0 += w1 * p.x; a1 += w1 * p.y;
        p = unpkh(v1.y); a2 += w1 * p.x; a3 += w1 * p.y;
        p = unpkh(v2.x); a0 += w2 * p.x; a1 += w2 * p.y;
        p = unpkh(v2.y); a2 += w2 * p.x; a3 += w2 * p.y;
        p = unpkh(v3.x); a0 += w3 * p.x; a1 += w3 * p.y;
        p = unpkh(v3.y); a2 += w3 * p.x; a3 += w3 * p.y;
    }
    for (; j < e1; ++j) {
        int s = cs[j];
        float w = dinv[s];
        uint2 v = xw2[(size_t)s * 64 + t];
        float2 p;
        p = unpkh(v.x); a0 += w * p.x; a1 += w * p.y;
        p = unpkh(v.y); a2 += w * p.x; a3 += w * p.y;
    }
    int c = 4 * t;
    float o0 = fmaxf(dd * a0 + b1[c], 0.f);
    float o1 = fmaxf(dd * a1 + b1[c + 1], 0.f);
    float o2 = fmaxf(dd * a2 + b1[c + 2], 0.f);
    float o3 = fmaxf(dd * a3 + b1[c + 3], 0.f);
    uint2 o;
    o.x = packh(o0, o1);
    o.y = packh(o2, o3);
    hb2[(size_t)d * 64 + t] = o;
}

// ---------------- GCN second aggregate: hA = Agg(h) fp16, 64 thr x uint2 ------------
__global__ void k_gcn_a2(const uint2* __restrict__ hb2, const float* __restrict__ dinv,
                         const int* __restrict__ rp, const int* __restrict__ cs,
                         uint2* __restrict__ hA2) {
    int d = blockIdx.x;
    int t = threadIdx.x;                         // 64 uint2 cols
    float dd = dinv[d];
    uint2 sv = hb2[(size_t)d * 64 + t];
    float2 s0 = unpkh(sv.x), s1 = unpkh(sv.y);
    float a0 = dd * s0.x, a1 = dd * s0.y, a2 = dd * s1.x, a3 = dd * s1.y;
    int e0 = rp[d], e1 = rp[d + 1];
    int j = e0;
    for (; j + 4 <= e1; j += 4) {
        int i0 = cs[j], i1 = cs[j + 1], i2 = cs[j + 2], i3 = cs[j + 3];
        float w0 = dinv[i0], w1 = dinv[i1], w2 = dinv[i2], w3 = dinv[i3];
        uint2 v0 = hb2[(size_t)i0 * 64 + t];
        uint2 v1 = hb2[(size_t)i1 * 64 + t];
        uint2 v2 = hb2[(size_t)i2 * 64 + t];
        uint2 v3 = hb2[(size_t)i3 * 64 + t];
        float2 p;
        p = unpkh(v0.x); a0 += w0 * p.x; a1 += w0 * p.y;
        p = unpkh(v0.y); a2 += w0 * p.x; a3 += w0 * p.y;
        p = unpkh(v1.x); a0 += w1 * p.x; a1 += w1 * p.y;
        p = unpkh(v1.y); a2 += w1 * p.x; a3 += w1 * p.y;
        p = unpkh(v2.x); a0 += w2 * p.x; a1 += w2 * p.y;
        p = unpkh(v2.y); a2 += w2 * p.x; a3 += w2 * p.y;
        p = unpkh(v3.x); a0 += w3 * p.x; a1 += w3 * p.y;
        p = unpkh(v3.y); a2 += w3 * p.x; a3 += w3 * p.y;
    }
    for (; j < e1; ++j) {
        int s = cs[j];
        float w = dinv[s];
        uint2 v = hb2[(size_t)s * 64 + t];
        float2 p;
        p = unpkh(v.x); a0 += w * p.x; a1 += w * p.y;
        p = unpkh(v.y); a2 += w * p.x; a3 += w * p.y;
    }
    uint2 o;
    o.x = packh(dd * a0, dd * a1);
    o.y = packh(dd * a2, dd * a3);
    hA2[(size_t)d * 64 + t] = o;
}

// ---------------- GAT layer1 logits (z = branch) ----------------
__global__ void k_gat_log1(const unsigned int* __restrict__ xwu, const float* __restrict__ a_s,
                           const float* __restrict__ a_d, float* __restrict__ as_n,
                           float* __restrict__ ad_n) {
    int br = blockIdx.z;
    int n = blockIdx.x;
    int hd = threadIdx.x >> 6, lane = threadIdx.x & 63;   // block 192
    const unsigned int* hp = xwu + (size_t)n * 384 + br * 192 + hd * 64;
    const float* av = a_s + br * 384 + hd * 128;
    const float* dv = a_d + br * 384 + hd * 128;
    float2 f = unpkh(hp[lane]);
    float ss = f.x * av[2 * lane] + f.y * av[2 * lane + 1];
    float sd = f.x * dv[2 * lane] + f.y * dv[2 * lane + 1];
    #pragma unroll
    for (int off = 32; off; off >>= 1) {
        ss += __shfl_down(ss, off);
        sd += __shfl_down(sd, off);
    }
    if (lane == 0) {
        as_n[(size_t)br * NN * 3 + n * 3 + hd] = ss;
        ad_n[(size_t)br * NN * 3 + n * 3 + hd] = sd;
    }
}

// ---------------- GAT layer2 logits (z = branch*2 + mtype) ----------------
__global__ void k_gat_log2(const unsigned short* __restrict__ h2gb, const float* __restrict__ asmu,
                           const float* __restrict__ aslv, const float* __restrict__ admu,
                           const float* __restrict__ adlv, float* __restrict__ as_n,
                           float* __restrict__ ad_n) {
    int zz = blockIdx.z;
    int br = zz >> 1, mt = zz & 1;
    int n = blockIdx.x;
    int hd = threadIdx.x >> 6, lane = threadIdx.x & 63;   // block 192
    const unsigned short* hp = h2gb + (size_t)br * NN * 384 + (size_t)n * 384 + mt * 192 + hd * 64;
    const float* av = (mt ? aslv : asmu) + br * 192 + hd * 64;
    const float* dv = (mt ? adlv : admu) + br * 192 + hd * 64;
    float hv = f16f(hp[lane]);
    float ss = hv * av[lane];
    float sd = hv * dv[lane];
    #pragma unroll
    for (int off = 32; off; off >>= 1) {
        ss += __shfl_down(ss, off);
        sd += __shfl_down(sd, off);
    }
    if (lane == 0) {
        as_n[(size_t)zz * NN * 3 + n * 3 + hd] = ss;
        ad_n[(size_t)zz * NN * 3 + n * 3 + hd] = sd;
    }
}

// ---------------- GAT softmax weights (z batched, wave per head) ----------------
__global__ void k_gat_attn(const float* __restrict__ as_n, const float* __restrict__ ad_n,
                           const int* __restrict__ rp, const int* __restrict__ cs,
                           float* __restrict__ w_csr, float* __restrict__ w_self, int E3) {
    int zz = blockIdx.z;
    as_n += (size_t)zz * NN * 3;
    ad_n += (size_t)zz * NN * 3;
    w_csr += (size_t)zz * E3;
    w_self += (size_t)zz * NN * 3;
    int d = blockIdx.x;
    int hd = threadIdx.x >> 6, lane = threadIdx.x & 63;   // block 192
    int e0 = rp[d], e1 = rp[d + 1];
    float add = ad_n[d * 3 + hd];
    float eself = lrelu(as_n[d * 3 + hd] + add);
    float mx = eself;
    for (int j = e0 + lane; j < e1; j += 64) {
        float e = lrelu(as_n[cs[j] * 3 + hd] + add);
        w_csr[(size_t)j * 3 + hd] = e;
        mx = fmaxf(mx, e);
    }
    #pragma unroll
    for (int off = 32; off; off >>= 1) mx = fmaxf(mx, __shfl_xor(mx, off));
    float sm = (lane == 0) ? __expf(eself - mx) : 0.f;
    for (int j = e0 + lane; j < e1; j += 64)
        sm += __expf(w_csr[(size_t)j * 3 + hd] - mx);
    #pragma unroll
    for (int off = 32; off; off >>= 1) sm += __shfl_xor(sm, off);
    float inv = 1.f / sm;
    if (lane == 0) w_self[d * 3 + hd] = __expf(eself - mx) * inv;
    for (int j = e0 + lane; j < e1; j += 64)
        w_csr[(size_t)j * 3 + hd] = __expf(w_csr[(size_t)j * 3 + hd] - mx) * inv;
}

// ---------------- GAT layer1 aggregate, both branches (192 thr x uint2) -------------
__global__ void k_gat_agg1(const uint2* __restrict__ xw2, const float* __restrict__ w_csr,
                           const float* __restrict__ w_self, const int* __restrict__ rp,
                           const int* __restrict__ cs, const float* __restrict__ b1,
                           uint2* __restrict__ h1s2, int E3) {
    int d = blockIdx.x;
    int t = threadIdx.x;                          // 192 uint2 cols (768 fp)
    int br = t >= 96 ? 1 : 0;
    int c = 4 * t - br * 384;                     // fp col within branch
    int hd = c >> 7;
    const float* wc = w_csr + (size_t)br * E3;
    float ws = w_self[(size_t)br * NN * 3 + d * 3 + hd];
    uint2 sv = xw2[(size_t)d * 192 + t];
    float2 s0 = unpkh(sv.x), s1 = unpkh(sv.y);
    float a0 = ws * s0.x, a1 = ws * s0.y, a2 = ws * s1.x, a3 = ws * s1.y;
    int e0 = rp[d], e1 = rp[d + 1];
    int j = e0;
    for (; j + 4 <= e1; j += 4) {
        int i0 = cs[j], i1 = cs[j + 1], i2 = cs[j + 2], i3 = cs[j + 3];
        float w0 = wc[(size_t)(j + 0) * 3 + hd];
        float w1 = wc[(size_t)(j + 1) * 3 + hd];
        float w2 = wc[(size_t)(j + 2) * 3 + hd];
        float w3 = wc[(size_t)(j + 3) * 3 + hd];
        uint2 v0 = xw2[(size_t)i0 * 192 + t];
        uint2 v1 = xw2[(size_t)i1 * 192 + t];
        uint2 v2 = xw2[(size_t)i2 * 192 + t];
        uint2 v3 = xw2[(size_t)i3 * 192 + t];
        float2 p;
        p = unpkh(v0.x); a0 += w0 * p.x; a1 += w0 * p.y;
        p = unpkh(v0.y); a2 += w0 * p.x; a3 += w0 * p.y;
        p = unpkh(v1.x); a0 += w1 * p.x; a1 += w1 * p.y;
        p = unpkh(v1.y); a2 += w1 * p.x; a3 += w1 * p.y;
        p = unpkh(v2.x); a0 += w2 * p.x; a1 += w2 * p.y;
        p = unpkh(v2.y); a2 += w2 * p.x; a3 += w2 * p.y;
        p = unpkh(v3.x); a0 += w3 * p.x; a1 += w3 * p.y;
        p = unpkh(v3.y); a2 += w3 * p.x; a3 += w3 * p.y;
    }
    for (; j < e1; ++j) {
        int s = cs[j];
        float w = wc[(size_t)j * 3 + hd];
        uint2 v = xw2[(size_t)s * 192 + t];
        float2 p;
        p = unpkh(v.x); a0 += w * p.x; a1 += w * p.y;
        p = unpkh(v.y); a2 += w * p.x; a3 += w * p.y;
    }
    int cg = 4 * t;                               // global fp col
    float o0 = fmaxf(a0 + b1[cg], 0.f);
    float o1 = fmaxf(a1 + b1[cg + 1], 0.f);
    float o2 = fmaxf(a2 + b1[cg + 2], 0.f);
    float o3 = fmaxf(a3 + b1[cg + 3], 0.f);
    uint2 o;
    o.x = packh(o0, o1);
    o.y = packh(o2, o3);
    h1s2[(size_t)d * 192 + t] = o;
}

// ---------------- GAT layer2 aggregate, both branches + mu/lv (192 thr) -------------
__global__ void k_gat_agg2(const uint2* __restrict__ h2g2, const float* __restrict__ w_csr,
                           const float* __restrict__ w_self, const int* __restrict__ rp,
                           const int* __restrict__ cs, const float* __restrict__ bmu,
                           const float* __restrict__ blv, float* __restrict__ mt_gat, int E3) {
    int d = blockIdx.x;
    int t = threadIdx.x;                          // 192: br(2) x 96 uint2 (384 fp each)
    int br = t >= 96 ? 1 : 0;
    int tb = t - br * 96;
    int mt = tb >= 48 ? 1 : 0;
    int c = 4 * tb - mt * 192;                    // fp col within (br,mt), 0..191
    int hd = c >> 6;
    const float* wc = w_csr + (size_t)(br * 2 + mt) * E3;
    float ws = w_self[(size_t)(br * 2 + mt) * NN * 3 + d * 3 + hd];
    const uint2* hp = h2g2 + (size_t)br * NN * 96;
    uint2 sv = hp[(size_t)d * 96 + tb];
    float2 s0 = unpkh(sv.x), s1 = unpkh(sv.y);
    float a0 = ws * s0.x, a1 = ws * s0.y, a2 = ws * s1.x, a3 = ws * s1.y;
    int e0 = rp[d], e1 = rp[d + 1];
    int j = e0;
    for (; j + 4 <= e1; j += 4) {
        int i0 = cs[j], i1 = cs[j + 1], i2 = cs[j + 2], i3 = cs[j + 3];
        float w0 = wc[(size_t)(j + 0) * 3 + hd];
        float w1 = wc[(size_t)(j + 1) * 3 + hd];
        float w2 = wc[(size_t)(j + 2) * 3 + hd];
        float w3 = wc[(size_t)(j + 3) * 3 + hd];
        uint2 v0 = hp[(size_t)i0 * 96 + tb];
        uint2 v1 = hp[(size_t)i1 * 96 + tb];
        uint2 v2 = hp[(size_t)i2 * 96 + tb];
        uint2 v3 = hp[(size_t)i3 * 96 + tb];
        float2 p;
        p = unpkh(v0.x); a0 += w0 * p.x; a1 += w0 * p.y;
        p = unpkh(v0.y); a2 += w0 * p.x; a3 += w0 * p.y;
        p = unpkh(v1.x); a0 += w1 * p.x; a1 += w1 * p.y;
        p = unpkh(v1.y); a2 += w1 * p.x; a3 += w1 * p.y;
        p = unpkh(v2.x); a0 += w2 * p.x; a1 += w2 * p.y;
        p = unpkh(v2.y); a2 += w2 * p.x; a3 += w2 * p.y;
        p = unpkh(v3.x); a0 += w3 * p.x; a1 += w3 * p.y;
        p = unpkh(v3.y); a2 += w3 * p.x; a3 += w3 * p.y;
    }
    for (; j < e1; ++j) {
        int s = cs[j];
        float w = wc[(size_t)j * 3 + hd];
        uint2 v = hp[(size_t)s * 96 + tb];
        float2 p;
        p = unpkh(v.x); a0 += w * p.x; a1 += w * p.y;
        p = unpkh(v.y); a2 += w * p.x; a3 += w * p.y;
    }
    __shared__ float red[768];                    // br*384 + mt*192 + c
    int rb = br * 384 + mt * 192 + c;
    red[rb] = a0; red[rb + 1] = a1; red[rb + 2] = a2; red[rb + 3] = a3;
    __syncthreads();
    if (t < 128) {
        #pragma unroll
        for (int q = 0; q < 2; ++q) {
            int o = t + q * 128;                  // 0..255
            int obr = o >> 7, omt = (o >> 6) & 1, dd = o & 63;
            int base = obr * 384 + omt * 192;
            float tot = red[base + dd] + red[base + 64 + dd] + red[base + 128 + dd];
            const float* bias = omt ? blv : bmu;
            float v = tot * (1.f / 3.f) + bias[obr * 64 + dd];
            mt_gat[((size_t)(obr * 2 + omt) * NN + d) * 64 + dd] = v;
        }
    }
}

// ---------------- finalize: bias, z, 4-way max, outputs + split-fp16 z2 -------------
__global__ void k_finalize(const float* __restrict__ muv_gcn, const float* __restrict__ gcn_bmu,
                           const float* __restrict__ gcn_blv, const float* __restrict__ mt_gat,
                           const float* __restrict__ eps_gcn, const float* __restrict__ eps_gat,
                           float* __restrict__ mu_o, float* __restrict__ lv_o,
                           unsigned short* __restrict__ z2) {
    int i = blockIdx.x * 256 + threadIdx.x;       // NN*64
    int d = i >> 6, c = i & 63;
    const size_t NN64 = (size_t)NN * 64;
    float mu, lv, zm;
    {
        float m = muv_gcn[(size_t)d * 128 + c] + gcn_bmu[c];
        float l = muv_gcn[(size_t)d * 128 + 64 + c] + gcn_blv[c];
        float z = m + eps_gcn[i] * __expf(l);
        mu = m; lv = l; zm = z;
    }
    {
        float m = muv_gcn[NN64 * 2 + (size_t)d * 128 + c] + gcn_bmu[64 + c];
        float l = muv_gcn[NN64 * 2 + (size_t)d * 128 + 64 + c] + gcn_blv[64 + c];
        float z = m + eps_gcn[NN64 + i] * __expf(l);
        mu = fmaxf(mu, m); lv = fmaxf(lv, l); zm = fmaxf(zm, z);
    }
    #pragma unroll
    for (int br = 0; br < 2; ++br) {
        float m = mt_gat[(size_t)(br * 2 + 0) * NN64 + i];
        float l = mt_gat[(size_t)(br * 2 + 1) * NN64 + i];
        float z = m + eps_gat[(size_t)br * NN64 + i] * __expf(l);
        mu = fmaxf(mu, m); lv = fmaxf(lv, l); zm = fmaxf(zm, z);
    }
    mu_o[i] = mu;
    lv_o[i] = lv;
    unsigned short hh, ll;
    splith(zm, hh, ll);
    z2[(size_t)d * 128 + c] = hh;
    z2[(size_t)d * 128 + 64 + c] = ll;
}

extern "C" void kernel_launch(void* const* d_in, const int* in_sizes, int n_in,
                              void* d_out, int out_size, void* d_ws, size_t ws_size,
                              hipStream_t stream) {
    const float* x  = (const float*)d_in[0];
    const int*   ei = (const int*)d_in[1];
    const int E = in_sizes[1] / 2;
    const int E3 = E * 3;
    const int* src = ei;
    const int* dst = ei + E;

    const float* gcn_W1  = (const float*)d_in[2];
    const float* gcn_b1  = (const float*)d_in[3];
    const float* gcn_Wmu = (const float*)d_in[4];
    const float* gcn_bmu = (const float*)d_in[5];
    const float* gcn_Wlv = (const float*)d_in[6];
    const float* gcn_blv = (const float*)d_in[7];
    const float* gat_W1  = (const float*)d_in[8];
    const float* gat_as1 = (const float*)d_in[9];
    const float* gat_ad1 = (const float*)d_in[10];
    const float* gat_b1  = (const float*)d_in[11];
    const float* gat_Wmu = (const float*)d_in[12];
    const float* gat_asmu= (const float*)d_in[13];
    const float* gat_admu= (const float*)d_in[14];
    const float* gat_bmu = (const float*)d_in[15];
    const float* gat_Wlv = (const float*)d_in[16];
    const float* gat_aslv= (const float*)d_in[17];
    const float* gat_adlv= (const float*)d_in[18];
    const float* gat_blv = (const float*)d_in[19];
    const float* eps_gcn = (const float*)d_in[20];
    const float* eps_gat = (const float*)d_in[21];

    // ---- workspace carve ----
    char* p = (char*)d_ws;
    auto alloc = [&](size_t bytes) {
        void* r = (void*)p;
        p += (bytes + 255) & ~(size_t)255;
        return r;
    };
    int*   cnt     = (int*)alloc((size_t)NN * 4);
    int*   cursor  = (int*)alloc((size_t)NN * 4);
    int*   row_ptr = (int*)alloc((size_t)(NN + 1) * 4);
    int*   csr_src = (int*)alloc((size_t)E * 4);
    float* dinv    = (float*)alloc((size_t)NN * 4);
    float* as_n1   = (float*)alloc((size_t)2 * NN * 3 * 4);
    float* ad_n1   = (float*)alloc((size_t)2 * NN * 3 * 4);
    float* wself1  = (float*)alloc((size_t)2 * NN * 3 * 4);
    float* wcsr1   = (float*)alloc((size_t)2 * E3 * 4);
    float* as_n2   = (float*)alloc((size_t)4 * NN * 3 * 4);
    float* ad_n2   = (float*)alloc((size_t)4 * NN * 3 * 4);
    float* wself2  = (float*)alloc((size_t)4 * NN * 3 * 4);
    float* wcsr2   = (float*)alloc((size_t)4 * E3 * 4);
    unsigned short* x2h      = (unsigned short*)alloc((size_t)NN * 512 * 2);
    unsigned short* wt_gcn1  = (unsigned short*)alloc((size_t)256 * 512 * 2);
    unsigned short* wt_gcnmuv= (unsigned short*)alloc((size_t)2 * 128 * 128 * 2);
    unsigned short* wt_gat1  = (unsigned short*)alloc((size_t)768 * 512 * 2);
    unsigned short* wt_gatmuv= (unsigned short*)alloc((size_t)2 * 384 * 384 * 2);
    unsigned short* xwb  = (unsigned short*)alloc((size_t)NN * 768 * 2);  // GCN uses ld 256
    unsigned short* hb   = (unsigned short*)alloc((size_t)NN * 256 * 2);
    unsigned short* hA   = (unsigned short*)alloc((size_t)NN * 256 * 2);
    float* muv_gcn = (float*)alloc((size_t)2 * NN * 128 * 4);
    unsigned short* h1s  = (unsigned short*)alloc((size_t)NN * 768 * 2);
    unsigned short* h2gb = (unsigned short*)alloc((size_t)2 * NN * 384 * 2);
    float* mt_gat  = (float*)alloc((size_t)4 * NN * 64 * 4);
    unsigned short* z2 = (unsigned short*)alloc((size_t)NN * 128 * 2);

    float* adj  = (float*)d_out;
    float* mu_o = adj + (size_t)NN * NN;
    float* lv_o = mu_o + (size_t)NN * 64;

    // ---- CSR build ----
    k_zero<<<(2 * NN + 255) / 256, 256, 0, stream>>>(cnt, 2 * NN);
    k_count<<<(E + 255) / 256, 256, 0, stream>>>(dst, cnt, E);
    k_dinv<<<(NN + 255) / 256, 256, 0, stream>>>(cnt, dinv);
    k_scan<<<1, 1024, 0, stream>>>(cnt, row_ptr);
    k_fill<<<(E + 255) / 256, 256, 0, stream>>>(src, dst, row_ptr, cursor, csr_src, E);

    // ---- precision prep (fp16) ----
    k_cvt_x<<<NN * 512 / 4 / 256, 256, 0, stream>>>(x, x2h);
    k_wT<<<dim3(16, 4, 2), 256, 0, stream>>>(gcn_W1, wt_gcn1, 512, 128, 0, 0, 128);
    k_wT<<<dim3(4, 2, 2), 256, 0, stream>>>(gcn_Wmu, wt_gcnmuv, 128, 64, (size_t)128 * 128, 0, 0);
    k_wT<<<dim3(4, 2, 2), 256, 0, stream>>>(gcn_Wlv, wt_gcnmuv, 128, 64, (size_t)128 * 128, 64, 0);
    k_wT<<<dim3(16, 12, 2), 256, 0, stream>>>(gat_W1, wt_gat1, 512, 384, 0, 0, 384);
    k_wT<<<dim3(12, 6, 2), 256, 0, stream>>>(gat_Wmu, wt_gatmuv, 384, 192, (size_t)384 * 384, 0, 0);
    k_wT<<<dim3(12, 6, 2), 256, 0, stream>>>(gat_Wlv, wt_gatmuv, 384, 192, (size_t)384 * 384, 192, 0);

    // ---- GCN (both branches batched) ----
    // g1: xwb[:, :256] = fp16(x2h @ wt_gcn1)  (K=512, N=256), ldc=256
    k_gemm2<1, 2><<<dim3(64, 4, 1), 256, 0, stream>>>(x2h, 0, 512, wt_gcn1, 0, 512,
                                                      xwb, 0, 256, 512);
    k_gcn_a1<<<NN, 64, 0, stream>>>((const uint2*)xwb, dinv, row_ptr, csr_src, gcn_b1,
                                    (uint2*)hb);
    k_gcn_a2<<<NN, 64, 0, stream>>>((const uint2*)hb, dinv, row_ptr, csr_src, (uint2*)hA);
    // g2: muv[z] = hA[z] @ wt_gcnmuv[z]  (K=128, N=128), fp32 out
    k_gemm2<1, 0><<<dim3(64, 2, 2), 256, 0, stream>>>(hA, 128, 256, wt_gcnmuv,
                                                      (size_t)128 * 128, 128,
                                                      muv_gcn, (size_t)NN * 128, 128, 128);

    // ---- GAT (both branches batched) ----
    // G1: xwb = fp16(x2h @ wt_gat1)  (K=512, N=768)
    k_gemm2<1, 2><<<dim3(64, 12, 1), 256, 0, stream>>>(x2h, 0, 512, wt_gat1, 0, 512,
                                                       xwb, 0, 768, 512);
    k_gat_log1<<<dim3(NN, 1, 2), 192, 0, stream>>>((const unsigned int*)xwb, gat_as1,
                                                   gat_ad1, as_n1, ad_n1);
    k_gat_attn<<<dim3(NN, 1, 2), 192, 0, stream>>>(as_n1, ad_n1, row_ptr, csr_src,
                                                   wcsr1, wself1, E3);
    k_gat_agg1<<<NN, 192, 0, stream>>>((const uint2*)xwb, wcsr1, wself1, row_ptr, csr_src,
                                       gat_b1, (uint2*)h1s, E3);
    // G2: h2gb[z] = fp16(h1s[z] @ wt_gatmuv[z])  (K=384, N=384)
    k_gemm2<1, 2><<<dim3(64, 6, 2), 256, 0, stream>>>(h1s, 384, 768, wt_gatmuv,
                                                      (size_t)384 * 384, 384,
                                                      h2gb, (size_t)NN * 384, 384, 384);
    k_gat_log2<<<dim3(NN, 1, 4), 192, 0, stream>>>(h2gb, gat_asmu, gat_aslv, gat_admu,
                                                   gat_adlv, as_n2, ad_n2);
    k_gat_attn<<<dim3(NN, 1, 4), 192, 0, stream>>>(as_n2, ad_n2, row_ptr, csr_src,
                                                   wcsr2, wself2, E3);
    k_gat_agg2<<<NN, 192, 0, stream>>>((const uint2*)h2gb, wcsr2, wself2, row_ptr, csr_src,
                                       gat_bmu, gat_blv, mt_gat, E3);

    // ---- finalize + adjacency (fp16 hi/lo 2-term) ----
    k_finalize<<<NN * 64 / 256, 256, 0, stream>>>(muv_gcn, gcn_bmu, gcn_blv, mt_gat,
                                                  eps_gcn, eps_gat, mu_o, lv_o, z2);
    k_gemm2<2, 1><<<dim3(64, 128, 1), 256, 0, stream>>>(z2, 0, 128, z2, 0, 128,
                                                        adj, 0, NN, 64);
}

// Round 11
// 362.311 us; speedup vs baseline: 1.0886x; 1.0886x over previous
//
#include <hip/hip_runtime.h>
#include <hip/hip_bf16.h>
#include <math.h>
#include <stddef.h>

#define NN 8192
#define NEG_SLOPE 0.2f

typedef _Float16 h8 __attribute__((ext_vector_type(8)));
typedef __attribute__((ext_vector_type(4))) float f32x4;

__device__ __forceinline__ float lrelu(float x) { return x > 0.f ? x : NEG_SLOPE * x; }
__device__ __forceinline__ float sigf(float x) { return 1.f / (1.f + __expf(-x)); }

__device__ __forceinline__ unsigned short f16b(float x) {
    _Float16 h = (_Float16)x;
    unsigned short u;
    __builtin_memcpy(&u, &h, 2);
    return u;
}
__device__ __forceinline__ float f16f(unsigned short u) {
    _Float16 h;
    __builtin_memcpy(&h, &u, 2);
    return (float)h;
}
__device__ __forceinline__ void splith(float x, unsigned short& hu, unsigned short& lu) {
    _Float16 h = (_Float16)x;
    float hf = (float)h;
    _Float16 l = (_Float16)(x - hf);
    __builtin_memcpy(&hu, &h, 2);
    __builtin_memcpy(&lu, &l, 2);
}
__device__ __forceinline__ float2 unpkh(unsigned int v) {
    float2 r;
    r.x = f16f((unsigned short)(v & 0xffffu));
    r.y = f16f((unsigned short)(v >> 16));
    return r;
}
__device__ __forceinline__ unsigned int packh(float a, float b) {
    return (unsigned int)f16b(a) | ((unsigned int)f16b(b) << 16);
}

// async global->LDS, 16B per lane; lds base must be wave-uniform
__device__ __forceinline__ void gll16(const unsigned short* g, unsigned short* l) {
    __builtin_amdgcn_global_load_lds(
        (const __attribute__((address_space(1))) unsigned int*)g,
        (__attribute__((address_space(3))) unsigned int*)l, 16, 0, 0);
}

// ---------------- CSR build ----------------
__global__ void k_zero(int* __restrict__ p, int n) {
    int i = blockIdx.x * blockDim.x + threadIdx.x;
    if (i < n) p[i] = 0;
}
__global__ void k_count(const int* __restrict__ dst, int* __restrict__ cnt, int E) {
    int i = blockIdx.x * blockDim.x + threadIdx.x;
    if (i < E) atomicAdd(&cnt[dst[i]], 1);
}
__global__ void k_dinv(const int* __restrict__ cnt, float* __restrict__ dinv) {
    int i = blockIdx.x * blockDim.x + threadIdx.x;
    if (i < NN) dinv[i] = rsqrtf((float)(cnt[i] + 1));
}
__global__ void k_scan(const int* __restrict__ cnt, int* __restrict__ row_ptr) {
    __shared__ int part[1024];
    int t = threadIdx.x;
    int base = t * 8;
    int loc[8];
    int s = 0;
    #pragma unroll
    for (int j = 0; j < 8; ++j) { loc[j] = s; s += cnt[base + j]; }
    part[t] = s;
    __syncthreads();
    for (int off = 1; off < 1024; off <<= 1) {
        int v = (t >= off) ? part[t - off] : 0;
        __syncthreads();
        part[t] += v;
        __syncthreads();
    }
    int pre = (t == 0) ? 0 : part[t - 1];
    #pragma unroll
    for (int j = 0; j < 8; ++j) row_ptr[base + j] = pre + loc[j];
    if (t == 1023) row_ptr[NN] = part[1023];
}
__global__ void k_fill(const int* __restrict__ src, const int* __restrict__ dst,
                       const int* __restrict__ row_ptr, int* __restrict__ cursor,
                       int* __restrict__ csr_src, int E) {
    int i = blockIdx.x * blockDim.x + threadIdx.x;
    if (i < E) {
        int d = dst[i];
        csr_src[row_ptr[d] + atomicAdd(&cursor[d], 1)] = src[i];
    }
}

// ---------------- x fp32 -> fp16 ----------------
__global__ void k_cvt_x(const float* __restrict__ x, unsigned short* __restrict__ xh) {
    int i = blockIdx.x * 256 + threadIdx.x;     // over NN*512/4
    int m = i >> 7, k4 = (i & 127) * 4;
    float4 v = *(const float4*)(x + (size_t)m * 512 + k4);
    ushort4 o;
    o.x = f16b(v.x); o.y = f16b(v.y); o.z = f16b(v.z); o.w = f16b(v.w);
    *(ushort4*)&xh[(size_t)m * 512 + k4] = o;
}

// W[z] [K,N] fp32 -> Wt fp16 rows (noff + z*noff_z + n) of length K
__global__ void k_wT(const float* __restrict__ W, unsigned short* __restrict__ Wt,
                     int K, int N, size_t wt_z_stride, int noff, int noff_z) {
    int b = blockIdx.z;
    W += (size_t)b * K * N;
    Wt += (size_t)b * wt_z_stride;
    int rowbase = noff + b * noff_z;
    int k0 = blockIdx.x * 32, n0 = blockIdx.y * 32;
    __shared__ float tl[32][33];
    int tid = threadIdx.x;
    int r = tid >> 5, cc = tid & 31;
    #pragma unroll
    for (int c = 0; c < 4; ++c)
        tl[r + c * 8][cc] = W[(size_t)(k0 + r + c * 8) * N + n0 + cc];
    __syncthreads();
    #pragma unroll
    for (int c = 0; c < 4; ++c) {
        int n = r + c * 8, k = cc;
        Wt[(size_t)(rowbase + n0 + n) * K + k0 + k] = f16b(tl[k][n]);
    }
}

// ---------------- fp16 MFMA GEMM, global_load_lds staging ----------------
template <int ROWS>
__device__ __forceinline__ void stage(const unsigned short* __restrict__ gbase, int lda,
                                      unsigned short* lds, int wid, int lane) {
    #pragma unroll
    for (int c = 0; c < ROWS / 32; ++c) {
        int chunk = c * 4 + wid;                // 1KB chunks
        int row = chunk * 8 + (lane >> 3);
        int g = (lane & 7) ^ (row & 7);
        gll16(gbase + (size_t)row * lda + g * 8, lds + chunk * 512);
    }
}
__device__ __forceinline__ h8 fragrh(const unsigned short* lds, int row, int kg) {
    return *(const h8*)(lds + row * 64 + ((kg ^ (row & 7)) * 8));
}

// TERMS: 1 = Ah*Bh; 2 = (Ah+Al)*Bh; 3 = Ah*Bh+Al*Bh+Ah*Bl
template <int TERMS, int EPI>   // EPI: 0 fp32, 1 fp32+sigmoid, 2 fp16
__global__ __launch_bounds__(256) void k_gemm2(
    const unsigned short* __restrict__ A2, size_t azs, int lda,
    const unsigned short* __restrict__ B2, size_t bzs, int ldb,
    void* __restrict__ Cv, size_t czs, int ldc, int K) {
    __shared__ __align__(16) unsigned short sAh[128 * 64];
    __shared__ __align__(16) unsigned short sBh[64 * 64];
    __shared__ __align__(16) unsigned short sAl[(TERMS >= 2) ? 128 * 64 : 8];
    __shared__ __align__(16) unsigned short sBl[(TERMS >= 3) ? 64 * 64 : 8];
    const int tid = threadIdx.x;
    const int wid = tid >> 6, lane = tid & 63;
    const int wr = wid >> 1, wc = wid & 1;
    const int lr = lane & 15, lg = lane >> 4;
    const int m0 = blockIdx.x * 128, n0 = blockIdx.y * 64;
    const int z = blockIdx.z;
    A2 += (size_t)z * azs;
    B2 += (size_t)z * bzs;

    const f32x4 zero4 = {0.f, 0.f, 0.f, 0.f};
    f32x4 acc[4][2];
    #pragma unroll
    for (int m = 0; m < 4; ++m)
        #pragma unroll
        for (int n = 0; n < 2; ++n) acc[m][n] = zero4;

    for (int k0 = 0; k0 < K; k0 += 64) {
        stage<128>(A2 + (size_t)m0 * lda + k0, lda, sAh, wid, lane);
        stage<64> (B2 + (size_t)n0 * ldb + k0, ldb, sBh, wid, lane);
        if (TERMS >= 2) stage<128>(A2 + (size_t)m0 * lda + K + k0, lda, sAl, wid, lane);
        if (TERMS >= 3) stage<64> (B2 + (size_t)n0 * ldb + K + k0, ldb, sBl, wid, lane);
        __syncthreads();
        #pragma unroll
        for (int ks = 0; ks < 2; ++ks) {
            const int kg = ks * 4 + lg;
            h8 ah[4], al[4], bh[2], bl[2];
            #pragma unroll
            for (int m = 0; m < 4; ++m) {
                int row = wr * 64 + m * 16 + lr;
                ah[m] = fragrh(sAh, row, kg);
                if (TERMS >= 2) al[m] = fragrh(sAl, row, kg);
            }
            #pragma unroll
            for (int n = 0; n < 2; ++n) {
                int row = wc * 32 + n * 16 + lr;
                bh[n] = fragrh(sBh, row, kg);
                if (TERMS >= 3) bl[n] = fragrh(sBl, row, kg);
            }
            #pragma unroll
            for (int m = 0; m < 4; ++m)
                #pragma unroll
                for (int n = 0; n < 2; ++n) {
                    acc[m][n] = __builtin_amdgcn_mfma_f32_16x16x32_f16(ah[m], bh[n], acc[m][n], 0, 0, 0);
                    if (TERMS >= 2)
                        acc[m][n] = __builtin_amdgcn_mfma_f32_16x16x32_f16(al[m], bh[n], acc[m][n], 0, 0, 0);
                    if (TERMS >= 3)
                        acc[m][n] = __builtin_amdgcn_mfma_f32_16x16x32_f16(ah[m], bl[n], acc[m][n], 0, 0, 0);
                }
        }
        __syncthreads();
    }
    #pragma unroll
    for (int m = 0; m < 4; ++m)
        #pragma unroll
        for (int n = 0; n < 2; ++n)
            #pragma unroll
            for (int j = 0; j < 4; ++j) {
                int row = m0 + wr * 64 + m * 16 + lg * 4 + j;
                int col = n0 + wc * 32 + n * 16 + lr;
                float o = acc[m][n][j];
                if (EPI == 1) {
                    ((float*)Cv + (size_t)z * czs)[(size_t)row * ldc + col] = sigf(o);
                } else if (EPI == 2) {
                    ((unsigned short*)Cv + (size_t)z * czs)[(size_t)row * ldc + col] = f16b(o);
                } else {
                    ((float*)Cv + (size_t)z * czs)[(size_t)row * ldc + col] = o;
                }
            }
}

// ---------------- GCN layer1 aggregate: h = relu(Agg(xwh)+b1), 64 thr x uint2 --------
__global__ void k_gcn_a1(const uint2* __restrict__ xw2, const float* __restrict__ dinv,
                         const int* __restrict__ rp, const int* __restrict__ cs,
                         const float* __restrict__ b1, uint2* __restrict__ hb2) {
    int d = blockIdx.x;
    int t = threadIdx.x;                         // 64 uint2 cols (256 fp)
    float dd = dinv[d];
    uint2 sv = xw2[(size_t)d * 64 + t];
    float2 s0 = unpkh(sv.x), s1 = unpkh(sv.y);
    float a0 = dd * s0.x, a1 = dd * s0.y, a2 = dd * s1.x, a3 = dd * s1.y;
    int e0 = rp[d], e1 = rp[d + 1];
    int j = e0;
    for (; j + 4 <= e1; j += 4) {
        int i0 = cs[j], i1 = cs[j + 1], i2 = cs[j + 2], i3 = cs[j + 3];
        float w0 = dinv[i0], w1 = dinv[i1], w2 = dinv[i2], w3 = dinv[i3];
        uint2 v0 = xw2[(size_t)i0 * 64 + t];
        uint2 v1 = xw2[(size_t)i1 * 64 + t];
        uint2 v2 = xw2[(size_t)i2 * 64 + t];
        uint2 v3 = xw2[(size_t)i3 * 64 + t];
        float2 p;
        p = unpkh(v0.x); a0 += w0 * p.x; a1 += w0 * p.y;
        p = unpkh(v0.y); a2 += w0 * p.x; a3 += w0 * p.y;
        p = unpkh(v1.x); a0 += w1 * p.x; a1 += w1 * p.y;
        p = unpkh(v1.y); a2 += w1 * p.x; a3 += w1 * p.y;
        p = unpkh(v2.x); a0 += w2 * p.x; a1 += w2 * p.y;
        p = unpkh(v2.y); a2 += w2 * p.x; a3 += w2 * p.y;
        p = unpkh(v3.x); a0 += w3 * p.x; a1 += w3 * p.y;
        p = unpkh(v3.y); a2 += w3 * p.x; a3 += w3 * p.y;
    }
    for (; j < e1; ++j) {
        int s = cs[j];
        float w = dinv[s];
        uint2 v = xw2[(size_t)s * 64 + t];
        float2 p;
        p = unpkh(v.x); a0 += w * p.x; a1 += w * p.y;
        p = unpkh(v.y); a2 += w * p.x; a3 += w * p.y;
    }
    int c = 4 * t;
    float o0 = fmaxf(dd * a0 + b1[c], 0.f);
    float o1 = fmaxf(dd * a1 + b1[c + 1], 0.f);
    float o2 = fmaxf(dd * a2 + b1[c + 2], 0.f);
    float o3 = fmaxf(dd * a3 + b1[c + 3], 0.f);
    uint2 o;
    o.x = packh(o0, o1);
    o.y = packh(o2, o3);
    hb2[(size_t)d * 64 + t] = o;
}

// ---------------- GCN second aggregate: hA = Agg(h) fp16, 64 thr x uint2 ------------
__global__ void k_gcn_a2(const uint2* __restrict__ hb2, const float* __restrict__ dinv,
                         const int* __restrict__ rp, const int* __restrict__ cs,
                         uint2* __restrict__ hA2) {
    int d = blockIdx.x;
    int t = threadIdx.x;                         // 64 uint2 cols
    float dd = dinv[d];
    uint2 sv = hb2[(size_t)d * 64 + t];
    float2 s0 = unpkh(sv.x), s1 = unpkh(sv.y);
    float a0 = dd * s0.x, a1 = dd * s0.y, a2 = dd * s1.x, a3 = dd * s1.y;
    int e0 = rp[d], e1 = rp[d + 1];
    int j = e0;
    for (; j + 4 <= e1; j += 4) {
        int i0 = cs[j], i1 = cs[j + 1], i2 = cs[j + 2], i3 = cs[j + 3];
        float w0 = dinv[i0], w1 = dinv[i1], w2 = dinv[i2], w3 = dinv[i3];
        uint2 v0 = hb2[(size_t)i0 * 64 + t];
        uint2 v1 = hb2[(size_t)i1 * 64 + t];
        uint2 v2 = hb2[(size_t)i2 * 64 + t];
        uint2 v3 = hb2[(size_t)i3 * 64 + t];
        float2 p;
        p = unpkh(v0.x); a0 += w0 * p.x; a1 += w0 * p.y;
        p = unpkh(v0.y); a2 += w0 * p.x; a3 += w0 * p.y;
        p = unpkh(v1.x); a0 += w1 * p.x; a1 += w1 * p.y;
        p = unpkh(v1.y); a2 += w1 * p.x; a3 += w1 * p.y;
        p = unpkh(v2.x); a0 += w2 * p.x; a1 += w2 * p.y;
        p = unpkh(v2.y); a2 += w2 * p.x; a3 += w2 * p.y;
        p = unpkh(v3.x); a0 += w3 * p.x; a1 += w3 * p.y;
        p = unpkh(v3.y); a2 += w3 * p.x; a3 += w3 * p.y;
    }
    for (; j < e1; ++j) {
        int s = cs[j];
        float w = dinv[s];
        uint2 v = hb2[(size_t)s * 64 + t];
        float2 p;
        p = unpkh(v.x); a0 += w * p.x; a1 += w * p.y;
        p = unpkh(v.y); a2 += w * p.x; a3 += w * p.y;
    }
    uint2 o;
    o.x = packh(dd * a0, dd * a1);
    o.y = packh(dd * a2, dd * a3);
    hA2[(size_t)d * 64 + t] = o;
}

// ---------------- GAT layer1 logits (z = branch) ----------------
__global__ void k_gat_log1(const unsigned int* __restrict__ xwu, const float* __restrict__ a_s,
                           const float* __restrict__ a_d, float* __restrict__ as_n,
                           float* __restrict__ ad_n) {
    int br = blockIdx.z;
    int n = blockIdx.x;
    int hd = threadIdx.x >> 6, lane = threadIdx.x & 63;   // block 192
    const unsigned int* hp = xwu + (size_t)n * 384 + br * 192 + hd * 64;
    const float* av = a_s + br * 384 + hd * 128;
    const float* dv = a_d + br * 384 + hd * 128;
    float2 f = unpkh(hp[lane]);
    float ss = f.x * av[2 * lane] + f.y * av[2 * lane + 1];
    float sd = f.x * dv[2 * lane] + f.y * dv[2 * lane + 1];
    #pragma unroll
    for (int off = 32; off; off >>= 1) {
        ss += __shfl_down(ss, off);
        sd += __shfl_down(sd, off);
    }
    if (lane == 0) {
        as_n[(size_t)br * NN * 3 + n * 3 + hd] = ss;
        ad_n[(size_t)br * NN * 3 + n * 3 + hd] = sd;
    }
}

// ---------------- GAT layer2 logits (z = branch*2 + mtype) ----------------
__global__ void k_gat_log2(const unsigned short* __restrict__ h2gb, const float* __restrict__ asmu,
                           const float* __restrict__ aslv, const float* __restrict__ admu,
                           const float* __restrict__ adlv, float* __restrict__ as_n,
                           float* __restrict__ ad_n) {
    int zz = blockIdx.z;
    int br = zz >> 1, mt = zz & 1;
    int n = blockIdx.x;
    int hd = threadIdx.x >> 6, lane = threadIdx.x & 63;   // block 192
    const unsigned short* hp = h2gb + (size_t)br * NN * 384 + (size_t)n * 384 + mt * 192 + hd * 64;
    const float* av = (mt ? aslv : asmu) + br * 192 + hd * 64;
    const float* dv = (mt ? adlv : admu) + br * 192 + hd * 64;
    float hv = f16f(hp[lane]);
    float ss = hv * av[lane];
    float sd = hv * dv[lane];
    #pragma unroll
    for (int off = 32; off; off >>= 1) {
        ss += __shfl_down(ss, off);
        sd += __shfl_down(sd, off);
    }
    if (lane == 0) {
        as_n[(size_t)zz * NN * 3 + n * 3 + hd] = ss;
        ad_n[(size_t)zz * NN * 3 + n * 3 + hd] = sd;
    }
}

// ---------------- GAT softmax weights (z batched, wave per head) ----------------
__global__ void k_gat_attn(const float* __restrict__ as_n, const float* __restrict__ ad_n,
                           const int* __restrict__ rp, const int* __restrict__ cs,
                           float* __restrict__ w_csr, float* __restrict__ w_self, int E3) {
    int zz = blockIdx.z;
    as_n += (size_t)zz * NN * 3;
    ad_n += (size_t)zz * NN * 3;
    w_csr += (size_t)zz * E3;
    w_self += (size_t)zz * NN * 3;
    int d = blockIdx.x;
    int hd = threadIdx.x >> 6, lane = threadIdx.x & 63;   // block 192
    int e0 = rp[d], e1 = rp[d + 1];
    float add = ad_n[d * 3 + hd];
    float eself = lrelu(as_n[d * 3 + hd] + add);
    float mx = eself;
    for (int j = e0 + lane; j < e1; j += 64) {
        float e = lrelu(as_n[cs[j] * 3 + hd] + add);
        w_csr[(size_t)j * 3 + hd] = e;
        mx = fmaxf(mx, e);
    }
    #pragma unroll
    for (int off = 32; off; off >>= 1) mx = fmaxf(mx, __shfl_xor(mx, off));
    float sm = (lane == 0) ? __expf(eself - mx) : 0.f;
    for (int j = e0 + lane; j < e1; j += 64)
        sm += __expf(w_csr[(size_t)j * 3 + hd] - mx);
    #pragma unroll
    for (int off = 32; off; off >>= 1) sm += __shfl_xor(sm, off);
    float inv = 1.f / sm;
    if (lane == 0) w_self[d * 3 + hd] = __expf(eself - mx) * inv;
    for (int j = e0 + lane; j < e1; j += 64)
        w_csr[(size_t)j * 3 + hd] = __expf(w_csr[(size_t)j * 3 + hd] - mx) * inv;
}

// ---------------- GAT layer1 aggregate, both branches (192 thr x uint2) -------------
__global__ void k_gat_agg1(const uint2* __restrict__ xw2, const float* __restrict__ w_csr,
                           const float* __restrict__ w_self, const int* __restrict__ rp,
                           const int* __restrict__ cs, const float* __restrict__ b1,
                           uint2* __restrict__ h1s2, int E3) {
    int d = blockIdx.x;
    int t = threadIdx.x;                          // 192 uint2 cols (768 fp)
    int br = t >= 96 ? 1 : 0;
    int c = 4 * t - br * 384;                     // fp col within branch
    int hd = c >> 7;
    const float* wc = w_csr + (size_t)br * E3;
    float ws = w_self[(size_t)br * NN * 3 + d * 3 + hd];
    uint2 sv = xw2[(size_t)d * 192 + t];
    float2 s0 = unpkh(sv.x), s1 = unpkh(sv.y);
    float a0 = ws * s0.x, a1 = ws * s0.y, a2 = ws * s1.x, a3 = ws * s1.y;
    int e0 = rp[d], e1 = rp[d + 1];
    int j = e0;
    for (; j + 4 <= e1; j += 4) {
        int i0 = cs[j], i1 = cs[j + 1], i2 = cs[j + 2], i3 = cs[j + 3];
        float w0 = wc[(size_t)(j + 0) * 3 + hd];
        float w1 = wc[(size_t)(j + 1) * 3 + hd];
        float w2 = wc[(size_t)(j + 2) * 3 + hd];
        float w3 = wc[(size_t)(j + 3) * 3 + hd];
        uint2 v0 = xw2[(size_t)i0 * 192 + t];
        uint2 v1 = xw2[(size_t)i1 * 192 + t];
        uint2 v2 = xw2[(size_t)i2 * 192 + t];
        uint2 v3 = xw2[(size_t)i3 * 192 + t];
        float2 p;
        p = unpkh(v0.x); a0 += w0 * p.x; a1 += w0 * p.y;
        p = unpkh(v0.y); a2 += w0 * p.x; a3 += w0 * p.y;
        p = unpkh(v1.x); a0 += w1 * p.x; a1 += w1 * p.y;
        p = unpkh(v1.y); a2 += w1 * p.x; a3 += w1 * p.y;
        p = unpkh(v2.x); a0 += w2 * p.x; a1 += w2 * p.y;
        p = unpkh(v2.y); a2 += w2 * p.x; a3 += w2 * p.y;
        p = unpkh(v3.x); a0 += w3 * p.x; a1 += w3 * p.y;
        p = unpkh(v3.y); a2 += w3 * p.x; a3 += w3 * p.y;
    }
    for (; j < e1; ++j) {
        int s = cs[j];
        float w = wc[(size_t)j * 3 + hd];
        uint2 v = xw2[(size_t)s * 192 + t];
        float2 p;
        p = unpkh(v.x); a0 += w * p.x; a1 += w * p.y;
        p = unpkh(v.y); a2 += w * p.x; a3 += w * p.y;
    }
    int cg = 4 * t;                               // global fp col
    float o0 = fmaxf(a0 + b1[cg], 0.f);
    float o1 = fmaxf(a1 + b1[cg + 1], 0.f);
    float o2 = fmaxf(a2 + b1[cg + 2], 0.f);
    float o3 = fmaxf(a3 + b1[cg + 3], 0.f);
    uint2 o;
    o.x = packh(o0, o1);
    o.y = packh(o2, o3);
    h1s2[(size_t)d * 192 + t] = o;
}

// ---------------- GAT layer2 aggregate, both branches + mu/lv (192 thr) -------------
__global__ void k_gat_agg2(const uint2* __restrict__ h2g2, const float* __restrict__ w_csr,
                           const float* __restrict__ w_self, const int* __restrict__ rp,
                           const int* __restrict__ cs, const float* __restrict__ bmu,
                           const float* __restrict__ blv, float* __restrict__ mt_gat, int E3) {
    int d = blockIdx.x;
    int t = threadIdx.x;                          // 192: br(2) x 96 uint2 (384 fp each)
    int br = t >= 96 ? 1 : 0;
    int tb = t - br * 96;
    int mt = tb >= 48 ? 1 : 0;
    int c = 4 * tb - mt * 192;                    // fp col within (br,mt), 0..191
    int hd = c >> 6;
    const float* wc = w_csr + (size_t)(br * 2 + mt) * E3;
    float ws = w_self[(size_t)(br * 2 + mt) * NN * 3 + d * 3 + hd];
    const uint2* hp = h2g2 + (size_t)br * NN * 96;
    uint2 sv = hp[(size_t)d * 96 + tb];
    float2 s0 = unpkh(sv.x), s1 = unpkh(sv.y);
    float a0 = ws * s0.x, a1 = ws * s0.y, a2 = ws * s1.x, a3 = ws * s1.y;
    int e0 = rp[d], e1 = rp[d + 1];
    int j = e0;
    for (; j + 4 <= e1; j += 4) {
        int i0 = cs[j], i1 = cs[j + 1], i2 = cs[j + 2], i3 = cs[j + 3];
        float w0 = wc[(size_t)(j + 0) * 3 + hd];
        float w1 = wc[(size_t)(j + 1) * 3 + hd];
        float w2 = wc[(size_t)(j + 2) * 3 + hd];
        float w3 = wc[(size_t)(j + 3) * 3 + hd];
        uint2 v0 = hp[(size_t)i0 * 96 + tb];
        uint2 v1 = hp[(size_t)i1 * 96 + tb];
        uint2 v2 = hp[(size_t)i2 * 96 + tb];
        uint2 v3 = hp[(size_t)i3 * 96 + tb];
        float2 p;
        p = unpkh(v0.x); a0 += w0 * p.x; a1 += w0 * p.y;
        p = unpkh(v0.y); a2 += w0 * p.x; a3 += w0 * p.y;
        p = unpkh(v1.x); a0 += w1 * p.x; a1 += w1 * p.y;
        p = unpkh(v1.y); a2 += w1 * p.x; a3 += w1 * p.y;
        p = unpkh(v2.x); a0 += w2 * p.x; a1 += w2 * p.y;
        p = unpkh(v2.y); a2 += w2 * p.x; a3 += w2 * p.y;
        p = unpkh(v3.x); a0 += w3 * p.x; a1 += w3 * p.y;
        p = unpkh(v3.y); a2 += w3 * p.x; a3 += w3 * p.y;
    }
    for (; j < e1; ++j) {
        int s = cs[j];
        float w = wc[(size_t)j * 3 + hd];
        uint2 v = hp[(size_t)s * 96 + tb];
        float2 p;
        p = unpkh(v.x); a0 += w * p.x; a1 += w * p.y;
        p = unpkh(v.y); a2 += w * p.x; a3 += w * p.y;
    }
    __shared__ float red[768];                    // br*384 + mt*192 + c
    int rb = br * 384 + mt * 192 + c;
    red[rb] = a0; red[rb + 1] = a1; red[rb + 2] = a2; red[rb + 3] = a3;
    __syncthreads();
    if (t < 128) {
        #pragma unroll
        for (int q = 0; q < 2; ++q) {
            int o = t + q * 128;                  // 0..255
            int obr = o >> 7, omt = (o >> 6) & 1, dd = o & 63;
            int base = obr * 384 + omt * 192;
            float tot = red[base + dd] + red[base + 64 + dd] + red[base + 128 + dd];
            const float* bias = omt ? blv : bmu;
            float v = tot * (1.f / 3.f) + bias[obr * 64 + dd];
            mt_gat[((size_t)(obr * 2 + omt) * NN + d) * 64 + dd] = v;
        }
    }
}

// ---------------- finalize: bias, z, 4-way max, outputs + split-fp16 z2 -------------
__global__ void k_finalize(const float* __restrict__ muv_gcn, const float* __restrict__ gcn_bmu,
                           const float* __restrict__ gcn_blv, const float* __restrict__ mt_gat,
                           const float* __restrict__ eps_gcn, const float* __restrict__ eps_gat,
                           float* __restrict__ mu_o, float* __restrict__ lv_o,
                           unsigned short* __restrict__ z2) {
    int i = blockIdx.x * 256 + threadIdx.x;       // NN*64
    int d = i >> 6, c = i & 63;
    const size_t NN64 = (size_t)NN * 64;
    float mu, lv, zm;
    {
        float m = muv_gcn[(size_t)d * 128 + c] + gcn_bmu[c];
        float l = muv_gcn[(size_t)d * 128 + 64 + c] + gcn_blv[c];
        float z = m + eps_gcn[i] * __expf(l);
        mu = m; lv = l; zm = z;
    }
    {
        float m = muv_gcn[NN64 * 2 + (size_t)d * 128 + c] + gcn_bmu[64 + c];
        float l = muv_gcn[NN64 * 2 + (size_t)d * 128 + 64 + c] + gcn_blv[64 + c];
        float z = m + eps_gcn[NN64 + i] * __expf(l);
        mu = fmaxf(mu, m); lv = fmaxf(lv, l); zm = fmaxf(zm, z);
    }
    #pragma unroll
    for (int br = 0; br < 2; ++br) {
        float m = mt_gat[(size_t)(br * 2 + 0) * NN64 + i];
        float l = mt_gat[(size_t)(br * 2 + 1) * NN64 + i];
        float z = m + eps_gat[(size_t)br * NN64 + i] * __expf(l);
        mu = fmaxf(mu, m); lv = fmaxf(lv, l); zm = fmaxf(zm, z);
    }
    mu_o[i] = mu;
    lv_o[i] = lv;
    unsigned short hh, ll;
    splith(zm, hh, ll);
    z2[(size_t)d * 128 + c] = hh;
    z2[(size_t)d * 128 + 64 + c] = ll;
}

extern "C" void kernel_launch(void* const* d_in, const int* in_sizes, int n_in,
                              void* d_out, int out_size, void* d_ws, size_t ws_size,
                              hipStream_t stream) {
    const float* x  = (const float*)d_in[0];
    const int*   ei = (const int*)d_in[1];
    const int E = in_sizes[1] / 2;
    const int E3 = E * 3;
    const int* src = ei;
    const int* dst = ei + E;

    const float* gcn_W1  = (const float*)d_in[2];
    const float* gcn_b1  = (const float*)d_in[3];
    const float* gcn_Wmu = (const float*)d_in[4];
    const float* gcn_bmu = (const float*)d_in[5];
    const float* gcn_Wlv = (const float*)d_in[6];
    const float* gcn_blv = (const float*)d_in[7];
    const float* gat_W1  = (const float*)d_in[8];
    const float* gat_as1 = (const float*)d_in[9];
    const float* gat_ad1 = (const float*)d_in[10];
    const float* gat_b1  = (const float*)d_in[11];
    const float* gat_Wmu = (const float*)d_in[12];
    const float* gat_asmu= (const float*)d_in[13];
    const float* gat_admu= (const float*)d_in[14];
    const float* gat_bmu = (const float*)d_in[15];
    const float* gat_Wlv = (const float*)d_in[16];
    const float* gat_aslv= (const float*)d_in[17];
    const float* gat_adlv= (const float*)d_in[18];
    const float* gat_blv = (const float*)d_in[19];
    const float* eps_gcn = (const float*)d_in[20];
    const float* eps_gat = (const float*)d_in[21];

    // ---- workspace carve ----
    char* p = (char*)d_ws;
    auto alloc = [&](size_t bytes) {
        void* r = (void*)p;
        p += (bytes + 255) & ~(size_t)255;
        return r;
    };
    int*   cnt     = (int*)alloc((size_t)NN * 4);
    int*   cursor  = (int*)alloc((size_t)NN * 4);
    int*   row_ptr = (int*)alloc((size_t)(NN + 1) * 4);
    int*   csr_src = (int*)alloc((size_t)E * 4);
    float* dinv    = (float*)alloc((size_t)NN * 4);
    float* as_n1   = (float*)alloc((size_t)2 * NN * 3 * 4);
    float* ad_n1   = (float*)alloc((size_t)2 * NN * 3 * 4);
    float* wself1  = (float*)alloc((size_t)2 * NN * 3 * 4);
    float* wcsr1   = (float*)alloc((size_t)2 * E3 * 4);
    float* as_n2   = (float*)alloc((size_t)4 * NN * 3 * 4);
    float* ad_n2   = (float*)alloc((size_t)4 * NN * 3 * 4);
    float* wself2  = (float*)alloc((size_t)4 * NN * 3 * 4);
    float* wcsr2   = (float*)alloc((size_t)4 * E3 * 4);
    unsigned short* x2h      = (unsigned short*)alloc((size_t)NN * 512 * 2);
    unsigned short* wt_gcn1  = (unsigned short*)alloc((size_t)256 * 512 * 2);
    unsigned short* wt_gcnmuv= (unsigned short*)alloc((size_t)2 * 128 * 128 * 2);
    unsigned short* wt_gat1  = (unsigned short*)alloc((size_t)768 * 512 * 2);
    unsigned short* wt_gatmuv= (unsigned short*)alloc((size_t)2 * 384 * 384 * 2);
    unsigned short* xwb  = (unsigned short*)alloc((size_t)NN * 768 * 2);  // GCN uses ld 256
    unsigned short* hb   = (unsigned short*)alloc((size_t)NN * 256 * 2);
    unsigned short* hA   = (unsigned short*)alloc((size_t)NN * 256 * 2);
    float* muv_gcn = (float*)alloc((size_t)2 * NN * 128 * 4);
    unsigned short* h1s  = (unsigned short*)alloc((size_t)NN * 768 * 2);
    unsigned short* h2gb = (unsigned short*)alloc((size_t)2 * NN * 384 * 2);
    float* mt_gat  = (float*)alloc((size_t)4 * NN * 64 * 4);
    unsigned short* z2 = (unsigned short*)alloc((size_t)NN * 128 * 2);

    float* adj  = (float*)d_out;
    float* mu_o = adj + (size_t)NN * NN;
    float* lv_o = mu_o + (size_t)NN * 64;

    // ---- CSR build ----
    k_zero<<<(2 * NN + 255) / 256, 256, 0, stream>>>(cnt, 2 * NN);
    k_count<<<(E + 255) / 256, 256, 0, stream>>>(dst, cnt, E);
    k_dinv<<<(NN + 255) / 256, 256, 0, stream>>>(cnt, dinv);
    k_scan<<<1, 1024, 0, stream>>>(cnt, row_ptr);
    k_fill<<<(E + 255) / 256, 256, 0, stream>>>(src, dst, row_ptr, cursor, csr_src, E);

    // ---- precision prep (fp16) ----
    k_cvt_x<<<NN * 512 / 4 / 256, 256, 0, stream>>>(x, x2h);
    k_wT<<<dim3(16, 4, 2), 256, 0, stream>>>(gcn_W1, wt_gcn1, 512, 128, 0, 0, 128);
    k_wT<<<dim3(4, 2, 2), 256, 0, stream>>>(gcn_Wmu, wt_gcnmuv, 128, 64, (size_t)128 * 128, 0, 0);
    k_wT<<<dim3(4, 2, 2), 256, 0, stream>>>(gcn_Wlv, wt_gcnmuv, 128, 64, (size_t)128 * 128, 64, 0);
    k_wT<<<dim3(16, 12, 2), 256, 0, stream>>>(gat_W1, wt_gat1, 512, 384, 0, 0, 384);
    k_wT<<<dim3(12, 6, 2), 256, 0, stream>>>(gat_Wmu, wt_gatmuv, 384, 192, (size_t)384 * 384, 0, 0);
    k_wT<<<dim3(12, 6, 2), 256, 0, stream>>>(gat_Wlv, wt_gatmuv, 384, 192, (size_t)384 * 384, 192, 0);

    // ---- GCN (both branches batched) ----
    // g1: xwb[:, :256] = fp16(x2h @ wt_gcn1)  (K=512, N=256), ldc=256
    k_gemm2<1, 2><<<dim3(64, 4, 1), 256, 0, stream>>>(x2h, 0, 512, wt_gcn1, 0, 512,
                                                      xwb, 0, 256, 512);
    k_gcn_a1<<<NN, 64, 0, stream>>>((const uint2*)xwb, dinv, row_ptr, csr_src, gcn_b1,
                                    (uint2*)hb);
    k_gcn_a2<<<NN, 64, 0, stream>>>((const uint2*)hb, dinv, row_ptr, csr_src, (uint2*)hA);
    // g2: muv[z] = hA[z] @ wt_gcnmuv[z]  (K=128, N=128), fp32 out
    k_gemm2<1, 0><<<dim3(64, 2, 2), 256, 0, stream>>>(hA, 128, 256, wt_gcnmuv,
                                                      (size_t)128 * 128, 128,
                                                      muv_gcn, (size_t)NN * 128, 128, 128);

    // ---- GAT (both branches batched) ----
    // G1: xwb = fp16(x2h @ wt_gat1)  (K=512, N=768)
    k_gemm2<1, 2><<<dim3(64, 12, 1), 256, 0, stream>>>(x2h, 0, 512, wt_gat1, 0, 512,
                                                       xwb, 0, 768, 512);
    k_gat_log1<<<dim3(NN, 1, 2), 192, 0, stream>>>((const unsigned int*)xwb, gat_as1,
                                                   gat_ad1, as_n1, ad_n1);
    k_gat_attn<<<dim3(NN, 1, 2), 192, 0, stream>>>(as_n1, ad_n1, row_ptr, csr_src,
                                                   wcsr1, wself1, E3);
    k_gat_agg1<<<NN, 192, 0, stream>>>((const uint2*)xwb, wcsr1, wself1, row_ptr, csr_src,
                                       gat_b1, (uint2*)h1s, E3);
    // G2: h2gb[z] = fp16(h1s[z] @ wt_gatmuv[z])  (K=384, N=384)
    k_gemm2<1, 2><<<dim3(64, 6, 2), 256, 0, stream>>>(h1s, 384, 768, wt_gatmuv,
                                                      (size_t)384 * 384, 384,
                                                      h2gb, (size_t)NN * 384, 384, 384);
    k_gat_log2<<<dim3(NN, 1, 4), 192, 0, stream>>>(h2gb, gat_asmu, gat_aslv, gat_admu,
                                                   gat_adlv, as_n2, ad_n2);
    k_gat_attn<<<dim3(NN, 1, 4), 192, 0, stream>>>(as_n2, ad_n2, row_ptr, csr_src,
                                                   wcsr2, wself2, E3);
    k_gat_agg2<<<NN, 192, 0, stream>>>((const uint2*)h2gb, wcsr2, wself2, row_ptr, csr_src,
                                       gat_bmu, gat_blv, mt_gat, E3);

    // ---- finalize + adjacency (fp16 hi/lo 2-term) ----
    k_finalize<<<NN * 64 / 256, 256, 0, stream>>>(muv_gcn, gcn_bmu, gcn_blv, mt_gat,
                                                  eps_gcn, eps_gat, mu_o, lv_o, z2);
    k_gemm2<2, 1><<<dim3(64, 128, 1), 256, 0, stream>>>(z2, 0, 128, z2, 0, 128,
                                                        adj, 0, NN, 64);
}

// Round 12
// 351.674 us; speedup vs baseline: 1.1215x; 1.0302x over previous
//
#include <hip/hip_runtime.h>
#include <hip/hip_bf16.h>
#include <math.h>
#include <stddef.h>

#define NN 8192
#define NEG_SLOPE 0.2f

typedef _Float16 h8 __attribute__((ext_vector_type(8)));
typedef __attribute__((ext_vector_type(4))) float f32x4;

__device__ __forceinline__ float lrelu(float x) { return x > 0.f ? x : NEG_SLOPE * x; }
__device__ __forceinline__ float sigf(float x) { return 1.f / (1.f + __expf(-x)); }

__device__ __forceinline__ unsigned short f16b(float x) {
    _Float16 h = (_Float16)x;
    unsigned short u;
    __builtin_memcpy(&u, &h, 2);
    return u;
}
__device__ __forceinline__ float f16f(unsigned short u) {
    _Float16 h;
    __builtin_memcpy(&h, &u, 2);
    return (float)h;
}
__device__ __forceinline__ void splith(float x, unsigned short& hu, unsigned short& lu) {
    _Float16 h = (_Float16)x;
    float hf = (float)h;
    _Float16 l = (_Float16)(x - hf);
    __builtin_memcpy(&hu, &h, 2);
    __builtin_memcpy(&lu, &l, 2);
}
__device__ __forceinline__ float2 unpkh(unsigned int v) {
    float2 r;
    r.x = f16f((unsigned short)(v & 0xffffu));
    r.y = f16f((unsigned short)(v >> 16));
    return r;
}
__device__ __forceinline__ unsigned int packh(float a, float b) {
    return (unsigned int)f16b(a) | ((unsigned int)f16b(b) << 16);
}

// async global->LDS, 16B per lane; lds base must be wave-uniform
__device__ __forceinline__ void gll16(const unsigned short* g, unsigned short* l) {
    __builtin_amdgcn_global_load_lds(
        (const __attribute__((address_space(1))) unsigned int*)g,
        (__attribute__((address_space(3))) unsigned int*)l, 16, 0, 0);
}

// ---------------- CSR build ----------------
__global__ void k_count(const int* __restrict__ dst, int* __restrict__ cnt, int E) {
    int i = blockIdx.x * blockDim.x + threadIdx.x;
    if (i < E) atomicAdd(&cnt[dst[i]], 1);
}
// scan + dinv fused
__global__ void k_scan(const int* __restrict__ cnt, int* __restrict__ row_ptr,
                       float* __restrict__ dinv) {
    __shared__ int part[1024];
    int t = threadIdx.x;
    int base = t * 8;
    int loc[8];
    int s = 0;
    #pragma unroll
    for (int j = 0; j < 8; ++j) {
        int cv = cnt[base + j];
        loc[j] = s;
        s += cv;
        dinv[base + j] = rsqrtf((float)(cv + 1));
    }
    part[t] = s;
    __syncthreads();
    for (int off = 1; off < 1024; off <<= 1) {
        int v = (t >= off) ? part[t - off] : 0;
        __syncthreads();
        part[t] += v;
        __syncthreads();
    }
    int pre = (t == 0) ? 0 : part[t - 1];
    #pragma unroll
    for (int j = 0; j < 8; ++j) row_ptr[base + j] = pre + loc[j];
    if (t == 1023) row_ptr[NN] = part[1023];
}
__global__ void k_fill(const int* __restrict__ src, const int* __restrict__ dst,
                       const int* __restrict__ row_ptr, int* __restrict__ cursor,
                       int* __restrict__ csr_src, int E) {
    int i = blockIdx.x * blockDim.x + threadIdx.x;
    if (i < E) {
        int d = dst[i];
        csr_src[row_ptr[d] + atomicAdd(&cursor[d], 1)] = src[i];
    }
}

// ---------------- x fp32 -> fp16 ----------------
__global__ void k_cvt_x(const float* __restrict__ x, unsigned short* __restrict__ xh) {
    int i = blockIdx.x * 256 + threadIdx.x;     // over NN*512/4
    int m = i >> 7, k4 = (i & 127) * 4;
    float4 v = *(const float4*)(x + (size_t)m * 512 + k4);
    ushort4 o;
    o.x = f16b(v.x); o.y = f16b(v.y); o.z = f16b(v.z); o.w = f16b(v.w);
    *(ushort4*)&xh[(size_t)m * 512 + k4] = o;
}

// W [K,N] fp32 -> Wt fp16 rows (noff + b*noff_z + n) of length K
__global__ void k_wT(const float* __restrict__ W, unsigned short* __restrict__ Wt,
                     int K, int N, size_t wt_z_stride, int noff, int noff_z) {
    int b = blockIdx.z;
    W += (size_t)b * K * N;
    Wt += (size_t)b * wt_z_stride;
    int rowbase = noff + b * noff_z;
    int k0 = blockIdx.x * 32, n0 = blockIdx.y * 32;
    __shared__ float tl[32][33];
    int tid = threadIdx.x;
    int r = tid >> 5, cc = tid & 31;
    #pragma unroll
    for (int c = 0; c < 4; ++c)
        tl[r + c * 8][cc] = W[(size_t)(k0 + r + c * 8) * N + n0 + cc];
    __syncthreads();
    #pragma unroll
    for (int c = 0; c < 4; ++c) {
        int n = r + c * 8, k = cc;
        Wt[(size_t)(rowbase + n0 + n) * K + k0 + k] = f16b(tl[k][n]);
    }
}

// merged mu/lv transpose: z = mt*2 + br; lv rows offset by lv_rowoff
__global__ void k_wT2(const float* __restrict__ Wmu, const float* __restrict__ Wlv,
                      unsigned short* __restrict__ Wt, int K, int N,
                      size_t wt_br_stride, int lv_rowoff) {
    int z = blockIdx.z;
    int mt = z >> 1, b = z & 1;
    const float* W = (mt ? Wlv : Wmu) + (size_t)b * K * N;
    Wt += (size_t)b * wt_br_stride;
    int rowbase = mt ? lv_rowoff : 0;
    int k0 = blockIdx.x * 32, n0 = blockIdx.y * 32;
    __shared__ float tl[32][33];
    int tid = threadIdx.x;
    int r = tid >> 5, cc = tid & 31;
    #pragma unroll
    for (int c = 0; c < 4; ++c)
        tl[r + c * 8][cc] = W[(size_t)(k0 + r + c * 8) * N + n0 + cc];
    __syncthreads();
    #pragma unroll
    for (int c = 0; c < 4; ++c) {
        int n = r + c * 8, k = cc;
        Wt[(size_t)(rowbase + n0 + n) * K + k0 + k] = f16b(tl[k][n]);
    }
}

// ---------------- fp16 MFMA GEMM, global_load_lds staging ----------------
template <int ROWS>
__device__ __forceinline__ void stage(const unsigned short* __restrict__ gbase, int lda,
                                      unsigned short* lds, int wid, int lane) {
    #pragma unroll
    for (int c = 0; c < ROWS / 32; ++c) {
        int chunk = c * 4 + wid;                // 1KB chunks
        int row = chunk * 8 + (lane >> 3);
        int g = (lane & 7) ^ (row & 7);
        gll16(gbase + (size_t)row * lda + g * 8, lds + chunk * 512);
    }
}
__device__ __forceinline__ h8 fragrh(const unsigned short* lds, int row, int kg) {
    return *(const h8*)(lds + row * 64 + ((kg ^ (row & 7)) * 8));
}

// TERMS: 1 = Ah*Bh; 2 = (Ah+Al)*Bh; 3 = Ah*Bh+Al*Bh+Ah*Bl
template <int TERMS, int EPI>   // EPI: 0 fp32, 1 fp32+sigmoid, 2 fp16
__global__ __launch_bounds__(256) void k_gemm2(
    const unsigned short* __restrict__ A2, size_t azs, int lda,
    const unsigned short* __restrict__ B2, size_t bzs, int ldb,
    void* __restrict__ Cv, size_t czs, int ldc, int K) {
    __shared__ __align__(16) unsigned short sAh[128 * 64];
    __shared__ __align__(16) unsigned short sBh[64 * 64];
    __shared__ __align__(16) unsigned short sAl[(TERMS >= 2) ? 128 * 64 : 8];
    __shared__ __align__(16) unsigned short sBl[(TERMS >= 3) ? 64 * 64 : 8];
    const int tid = threadIdx.x;
    const int wid = tid >> 6, lane = tid & 63;
    const int wr = wid >> 1, wc = wid & 1;
    const int lr = lane & 15, lg = lane >> 4;
    const int m0 = blockIdx.x * 128, n0 = blockIdx.y * 64;
    const int z = blockIdx.z;
    A2 += (size_t)z * azs;
    B2 += (size_t)z * bzs;

    const f32x4 zero4 = {0.f, 0.f, 0.f, 0.f};
    f32x4 acc[4][2];
    #pragma unroll
    for (int m = 0; m < 4; ++m)
        #pragma unroll
        for (int n = 0; n < 2; ++n) acc[m][n] = zero4;

    for (int k0 = 0; k0 < K; k0 += 64) {
        stage<128>(A2 + (size_t)m0 * lda + k0, lda, sAh, wid, lane);
        stage<64> (B2 + (size_t)n0 * ldb + k0, ldb, sBh, wid, lane);
        if (TERMS >= 2) stage<128>(A2 + (size_t)m0 * lda + K + k0, lda, sAl, wid, lane);
        if (TERMS >= 3) stage<64> (B2 + (size_t)n0 * ldb + K + k0, ldb, sBl, wid, lane);
        __syncthreads();
        #pragma unroll
        for (int ks = 0; ks < 2; ++ks) {
            const int kg = ks * 4 + lg;
            h8 ah[4], al[4], bh[2], bl[2];
            #pragma unroll
            for (int m = 0; m < 4; ++m) {
                int row = wr * 64 + m * 16 + lr;
                ah[m] = fragrh(sAh, row, kg);
                if (TERMS >= 2) al[m] = fragrh(sAl, row, kg);
            }
            #pragma unroll
            for (int n = 0; n < 2; ++n) {
                int row = wc * 32 + n * 16 + lr;
                bh[n] = fragrh(sBh, row, kg);
                if (TERMS >= 3) bl[n] = fragrh(sBl, row, kg);
            }
            #pragma unroll
            for (int m = 0; m < 4; ++m)
                #pragma unroll
                for (int n = 0; n < 2; ++n) {
                    acc[m][n] = __builtin_amdgcn_mfma_f32_16x16x32_f16(ah[m], bh[n], acc[m][n], 0, 0, 0);
                    if (TERMS >= 2)
                        acc[m][n] = __builtin_amdgcn_mfma_f32_16x16x32_f16(al[m], bh[n], acc[m][n], 0, 0, 0);
                    if (TERMS >= 3)
                        acc[m][n] = __builtin_amdgcn_mfma_f32_16x16x32_f16(ah[m], bl[n], acc[m][n], 0, 0, 0);
                }
        }
        __syncthreads();
    }
    #pragma unroll
    for (int m = 0; m < 4; ++m)
        #pragma unroll
        for (int n = 0; n < 2; ++n)
            #pragma unroll
            for (int j = 0; j < 4; ++j) {
                int row = m0 + wr * 64 + m * 16 + lg * 4 + j;
                int col = n0 + wc * 32 + n * 16 + lr;
                float o = acc[m][n][j];
                if (EPI == 1) {
                    ((float*)Cv + (size_t)z * czs)[(size_t)row * ldc + col] = sigf(o);
                } else if (EPI == 2) {
                    ((unsigned short*)Cv + (size_t)z * czs)[(size_t)row * ldc + col] = f16b(o);
                } else {
                    ((float*)Cv + (size_t)z * czs)[(size_t)row * ldc + col] = o;
                }
            }
}

// ---------------- GCN layer1 aggregate: h = relu(Agg(xwh)+b1), 64 thr x uint2 --------
__global__ void k_gcn_a1(const uint2* __restrict__ xw2, const float* __restrict__ dinv,
                         const int* __restrict__ rp, const int* __restrict__ cs,
                         const float* __restrict__ b1, uint2* __restrict__ hb2) {
    int d = blockIdx.x;
    int t = threadIdx.x;                         // 64 uint2 cols (256 fp)
    float dd = dinv[d];
    uint2 sv = xw2[(size_t)d * 64 + t];
    float2 s0 = unpkh(sv.x), s1 = unpkh(sv.y);
    float a0 = dd * s0.x, a1 = dd * s0.y, a2 = dd * s1.x, a3 = dd * s1.y;
    int e0 = rp[d], e1 = rp[d + 1];
    int j = e0;
    for (; j + 8 <= e1; j += 8) {
        int idx[8]; float w[8]; uint2 v[8];
        #pragma unroll
        for (int q = 0; q < 8; ++q) idx[q] = cs[j + q];
        #pragma unroll
        for (int q = 0; q < 8; ++q) w[q] = dinv[idx[q]];
        #pragma unroll
        for (int q = 0; q < 8; ++q) v[q] = xw2[(size_t)idx[q] * 64 + t];
        #pragma unroll
        for (int q = 0; q < 8; ++q) {
            float2 p;
            p = unpkh(v[q].x); a0 += w[q] * p.x; a1 += w[q] * p.y;
            p = unpkh(v[q].y); a2 += w[q] * p.x; a3 += w[q] * p.y;
        }
    }
    for (; j + 4 <= e1; j += 4) {
        int i0 = cs[j], i1 = cs[j + 1], i2 = cs[j + 2], i3 = cs[j + 3];
        float w0 = dinv[i0], w1 = dinv[i1], w2 = dinv[i2], w3 = dinv[i3];
        uint2 v0 = xw2[(size_t)i0 * 64 + t];
        uint2 v1 = xw2[(size_t)i1 * 64 + t];
        uint2 v2 = xw2[(size_t)i2 * 64 + t];
        uint2 v3 = xw2[(size_t)i3 * 64 + t];
        float2 p;
        p = unpkh(v0.x); a0 += w0 * p.x; a1 += w0 * p.y;
        p = unpkh(v0.y); a2 += w0 * p.x; a3 += w0 * p.y;
        p = unpkh(v1.x); a0 += w1 * p.x; a1 += w1 * p.y;
        p = unpkh(v1.y); a2 += w1 * p.x; a3 += w1 * p.y;
        p = unpkh(v2.x); a0 += w2 * p.x; a1 += w2 * p.y;
        p = unpkh(v2.y); a2 += w2 * p.x; a3 += w2 * p.y;
        p = unpkh(v3.x); a0 += w3 * p.x; a1 += w3 * p.y;
        p = unpkh(v3.y); a2 += w3 * p.x; a3 += w3 * p.y;
    }
    for (; j < e1; ++j) {
        int s = cs[j];
        float w = dinv[s];
        uint2 v = xw2[(size_t)s * 64 + t];
        float2 p;
        p = unpkh(v.x); a0 += w * p.x; a1 += w * p.y;
        p = unpkh(v.y); a2 += w * p.x; a3 += w * p.y;
    }
    int c = 4 * t;
    float o0 = fmaxf(dd * a0 + b1[c], 0.f);
    float o1 = fmaxf(dd * a1 + b1[c + 1], 0.f);
    float o2 = fmaxf(dd * a2 + b1[c + 2], 0.f);
    float o3 = fmaxf(dd * a3 + b1[c + 3], 0.f);
    uint2 o;
    o.x = packh(o0, o1);
    o.y = packh(o2, o3);
    hb2[(size_t)d * 64 + t] = o;
}

// ---------------- GCN second aggregate: hA = Agg(h) fp16, 64 thr x uint2 ------------
__global__ void k_gcn_a2(const uint2* __restrict__ hb2, const float* __restrict__ dinv,
                         const int* __restrict__ rp, const int* __restrict__ cs,
                         uint2* __restrict__ hA2) {
    int d = blockIdx.x;
    int t = threadIdx.x;                         // 64 uint2 cols
    float dd = dinv[d];
    uint2 sv = hb2[(size_t)d * 64 + t];
    float2 s0 = unpkh(sv.x), s1 = unpkh(sv.y);
    float a0 = dd * s0.x, a1 = dd * s0.y, a2 = dd * s1.x, a3 = dd * s1.y;
    int e0 = rp[d], e1 = rp[d + 1];
    int j = e0;
    for (; j + 8 <= e1; j += 8) {
        int idx[8]; float w[8]; uint2 v[8];
        #pragma unroll
        for (int q = 0; q < 8; ++q) idx[q] = cs[j + q];
        #pragma unroll
        for (int q = 0; q < 8; ++q) w[q] = dinv[idx[q]];
        #pragma unroll
        for (int q = 0; q < 8; ++q) v[q] = hb2[(size_t)idx[q] * 64 + t];
        #pragma unroll
        for (int q = 0; q < 8; ++q) {
            float2 p;
            p = unpkh(v[q].x); a0 += w[q] * p.x; a1 += w[q] * p.y;
            p = unpkh(v[q].y); a2 += w[q] * p.x; a3 += w[q] * p.y;
        }
    }
    for (; j + 4 <= e1; j += 4) {
        int i0 = cs[j], i1 = cs[j + 1], i2 = cs[j + 2], i3 = cs[j + 3];
        float w0 = dinv[i0], w1 = dinv[i1], w2 = dinv[i2], w3 = dinv[i3];
        uint2 v0 = hb2[(size_t)i0 * 64 + t];
        uint2 v1 = hb2[(size_t)i1 * 64 + t];
        uint2 v2 = hb2[(size_t)i2 * 64 + t];
        uint2 v3 = hb2[(size_t)i3 * 64 + t];
        float2 p;
        p = unpkh(v0.x); a0 += w0 * p.x; a1 += w0 * p.y;
        p = unpkh(v0.y); a2 += w0 * p.x; a3 += w0 * p.y;
        p = unpkh(v1.x); a0 += w1 * p.x; a1 += w1 * p.y;
        p = unpkh(v1.y); a2 += w1 * p.x; a3 += w1 * p.y;
        p = unpkh(v2.x); a0 += w2 * p.x; a1 += w2 * p.y;
        p = unpkh(v2.y); a2 += w2 * p.x; a3 += w2 * p.y;
        p = unpkh(v3.x); a0 += w3 * p.x; a1 += w3 * p.y;
        p = unpkh(v3.y); a2 += w3 * p.x; a3 += w3 * p.y;
    }
    for (; j < e1; ++j) {
        int s = cs[j];
        float w = dinv[s];
        uint2 v = hb2[(size_t)s * 64 + t];
        float2 p;
        p = unpkh(v.x); a0 += w * p.x; a1 += w * p.y;
        p = unpkh(v.y); a2 += w * p.x; a3 += w * p.y;
    }
    uint2 o;
    o.x = packh(dd * a0, dd * a1);
    o.y = packh(dd * a2, dd * a3);
    hA2[(size_t)d * 64 + t] = o;
}

// ---------------- GAT layer1 logits (z = branch) ----------------
__global__ void k_gat_log1(const unsigned int* __restrict__ xwu, const float* __restrict__ a_s,
                           const float* __restrict__ a_d, float* __restrict__ as_n,
                           float* __restrict__ ad_n) {
    int br = blockIdx.z;
    int n = blockIdx.x;
    int hd = threadIdx.x >> 6, lane = threadIdx.x & 63;   // block 192
    const unsigned int* hp = xwu + (size_t)n * 384 + br * 192 + hd * 64;
    const float* av = a_s + br * 384 + hd * 128;
    const float* dv = a_d + br * 384 + hd * 128;
    float2 f = unpkh(hp[lane]);
    float ss = f.x * av[2 * lane] + f.y * av[2 * lane + 1];
    float sd = f.x * dv[2 * lane] + f.y * dv[2 * lane + 1];
    #pragma unroll
    for (int off = 32; off; off >>= 1) {
        ss += __shfl_down(ss, off);
        sd += __shfl_down(sd, off);
    }
    if (lane == 0) {
        as_n[(size_t)br * NN * 3 + n * 3 + hd] = ss;
        ad_n[(size_t)br * NN * 3 + n * 3 + hd] = sd;
    }
}

// ---------------- GAT layer2 logits (z = branch*2 + mtype) ----------------
__global__ void k_gat_log2(const unsigned short* __restrict__ h2gb, const float* __restrict__ asmu,
                           const float* __restrict__ aslv, const float* __restrict__ admu,
                           const float* __restrict__ adlv, float* __restrict__ as_n,
                           float* __restrict__ ad_n) {
    int zz = blockIdx.z;
    int br = zz >> 1, mt = zz & 1;
    int n = blockIdx.x;
    int hd = threadIdx.x >> 6, lane = threadIdx.x & 63;   // block 192
    const unsigned short* hp = h2gb + (size_t)br * NN * 384 + (size_t)n * 384 + mt * 192 + hd * 64;
    const float* av = (mt ? aslv : asmu) + br * 192 + hd * 64;
    const float* dv = (mt ? adlv : admu) + br * 192 + hd * 64;
    float hv = f16f(hp[lane]);
    float ss = hv * av[lane];
    float sd = hv * dv[lane];
    #pragma unroll
    for (int off = 32; off; off >>= 1) {
        ss += __shfl_down(ss, off);
        sd += __shfl_down(sd, off);
    }
    if (lane == 0) {
        as_n[(size_t)zz * NN * 3 + n * 3 + hd] = ss;
        ad_n[(size_t)zz * NN * 3 + n * 3 + hd] = sd;
    }
}

// ---------------- GAT softmax weights (z batched, wave per head) ----------------
__global__ void k_gat_attn(const float* __restrict__ as_n, const float* __restrict__ ad_n,
                           const int* __restrict__ rp, const int* __restrict__ cs,
                           float* __restrict__ w_csr, float* __restrict__ w_self, int E3) {
    int zz = blockIdx.z;
    as_n += (size_t)zz * NN * 3;
    ad_n += (size_t)zz * NN * 3;
    w_csr += (size_t)zz * E3;
    w_self += (size_t)zz * NN * 3;
    int d = blockIdx.x;
    int hd = threadIdx.x >> 6, lane = threadIdx.x & 63;   // block 192
    int e0 = rp[d], e1 = rp[d + 1];
    float add = ad_n[d * 3 + hd];
    float eself = lrelu(as_n[d * 3 + hd] + add);
    float mx = eself;
    for (int j = e0 + lane; j < e1; j += 64) {
        float e = lrelu(as_n[cs[j] * 3 + hd] + add);
        w_csr[(size_t)j * 3 + hd] = e;
        mx = fmaxf(mx, e);
    }
    #pragma unroll
    for (int off = 32; off; off >>= 1) mx = fmaxf(mx, __shfl_xor(mx, off));
    float sm = (lane == 0) ? __expf(eself - mx) : 0.f;
    for (int j = e0 + lane; j < e1; j += 64)
        sm += __expf(w_csr[(size_t)j * 3 + hd] - mx);
    #pragma unroll
    for (int off = 32; off; off >>= 1) sm += __shfl_xor(sm, off);
    float inv = 1.f / sm;
    if (lane == 0) w_self[d * 3 + hd] = __expf(eself - mx) * inv;
    for (int j = e0 + lane; j < e1; j += 64)
        w_csr[(size_t)j * 3 + hd] = __expf(w_csr[(size_t)j * 3 + hd] - mx) * inv;
}

// ---------------- GAT layer1 aggregate, both branches (192 thr x uint2) -------------
__global__ void k_gat_agg1(const uint2* __restrict__ xw2, const float* __restrict__ w_csr,
                           const float* __restrict__ w_self, const int* __restrict__ rp,
                           const int* __restrict__ cs, const float* __restrict__ b1,
                           uint2* __restrict__ h1s2, int E3) {
    int d = blockIdx.x;
    int t = threadIdx.x;                          // 192 uint2 cols (768 fp)
    int br = t >= 96 ? 1 : 0;
    int c = 4 * t - br * 384;                     // fp col within branch
    int hd = c >> 7;
    const float* wc = w_csr + (size_t)br * E3;
    float ws = w_self[(size_t)br * NN * 3 + d * 3 + hd];
    uint2 sv = xw2[(size_t)d * 192 + t];
    float2 s0 = unpkh(sv.x), s1 = unpkh(sv.y);
    float a0 = ws * s0.x, a1 = ws * s0.y, a2 = ws * s1.x, a3 = ws * s1.y;
    int e0 = rp[d], e1 = rp[d + 1];
    int j = e0;
    for (; j + 8 <= e1; j += 8) {
        int idx[8]; float w[8]; uint2 v[8];
        #pragma unroll
        for (int q = 0; q < 8; ++q) idx[q] = cs[j + q];
        #pragma unroll
        for (int q = 0; q < 8; ++q) w[q] = wc[(size_t)(j + q) * 3 + hd];
        #pragma unroll
        for (int q = 0; q < 8; ++q) v[q] = xw2[(size_t)idx[q] * 192 + t];
        #pragma unroll
        for (int q = 0; q < 8; ++q) {
            float2 p;
            p = unpkh(v[q].x); a0 += w[q] * p.x; a1 += w[q] * p.y;
            p = unpkh(v[q].y); a2 += w[q] * p.x; a3 += w[q] * p.y;
        }
    }
    for (; j + 4 <= e1; j += 4) {
        int i0 = cs[j], i1 = cs[j + 1], i2 = cs[j + 2], i3 = cs[j + 3];
        float w0 = wc[(size_t)(j + 0) * 3 + hd];
        float w1 = wc[(size_t)(j + 1) * 3 + hd];
        float w2 = wc[(size_t)(j + 2) * 3 + hd];
        float w3 = wc[(size_t)(j + 3) * 3 + hd];
        uint2 v0 = xw2[(size_t)i0 * 192 + t];
        uint2 v1 = xw2[(size_t)i1 * 192 + t];
        uint2 v2 = xw2[(size_t)i2 * 192 + t];
        uint2 v3 = xw2[(size_t)i3 * 192 + t];
        float2 p;
        p = unpkh(v0.x); a0 += w0 * p.x; a1 += w0 * p.y;
        p = unpkh(v0.y); a2 += w0 * p.x; a3 += w0 * p.y;
        p = unpkh(v1.x); a0 += w1 * p.x; a1 += w1 * p.y;
        p = unpkh(v1.y); a2 += w1 * p.x; a3 += w1 * p.y;
        p = unpkh(v2.x); a0 += w2 * p.x; a1 += w2 * p.y;
        p = unpkh(v2.y); a2 += w2 * p.x; a3 += w2 * p.y;
        p = unpkh(v3.x); a0 += w3 * p.x; a1 += w3 * p.y;
        p = unpkh(v3.y); a2 += w3 * p.x; a3 += w3 * p.y;
    }
    for (; j < e1; ++j) {
        int s = cs[j];
        float w = wc[(size_t)j * 3 + hd];
        uint2 v = xw2[(size_t)s * 192 + t];
        float2 p;
        p = unpkh(v.x); a0 += w * p.x; a1 += w * p.y;
        p = unpkh(v.y); a2 += w * p.x; a3 += w * p.y;
    }
    int cg = 4 * t;                               // global fp col
    float o0 = fmaxf(a0 + b1[cg], 0.f);
    float o1 = fmaxf(a1 + b1[cg + 1], 0.f);
    float o2 = fmaxf(a2 + b1[cg + 2], 0.f);
    float o3 = fmaxf(a3 + b1[cg + 3], 0.f);
    uint2 o;
    o.x = packh(o0, o1);
    o.y = packh(o2, o3);
    h1s2[(size_t)d * 192 + t] = o;
}

// ---------------- GAT layer2 aggregate, both branches + mu/lv (192 thr) -------------
__global__ void k_gat_agg2(const uint2* __restrict__ h2g2, const float* __restrict__ w_csr,
                           const float* __restrict__ w_self, const int* __restrict__ rp,
                           const int* __restrict__ cs, const float* __restrict__ bmu,
                           const float* __restrict__ blv, float* __restrict__ mt_gat, int E3) {
    int d = blockIdx.x;
    int t = threadIdx.x;                          // 192: br(2) x 96 uint2 (384 fp each)
    int br = t >= 96 ? 1 : 0;
    int tb = t - br * 96;
    int mt = tb >= 48 ? 1 : 0;
    int c = 4 * tb - mt * 192;                    // fp col within (br,mt), 0..191
    int hd = c >> 6;
    const float* wc = w_csr + (size_t)(br * 2 + mt) * E3;
    float ws = w_self[(size_t)(br * 2 + mt) * NN * 3 + d * 3 + hd];
    const uint2* hp = h2g2 + (size_t)br * NN * 96;
    uint2 sv = hp[(size_t)d * 96 + tb];
    float2 s0 = unpkh(sv.x), s1 = unpkh(sv.y);
    float a0 = ws * s0.x, a1 = ws * s0.y, a2 = ws * s1.x, a3 = ws * s1.y;
    int e0 = rp[d], e1 = rp[d + 1];
    int j = e0;
    for (; j + 8 <= e1; j += 8) {
        int idx[8]; float w[8]; uint2 v[8];
        #pragma unroll
        for (int q = 0; q < 8; ++q) idx[q] = cs[j + q];
        #pragma unroll
        for (int q = 0; q < 8; ++q) w[q] = wc[(size_t)(j + q) * 3 + hd];
        #pragma unroll
        for (int q = 0; q < 8; ++q) v[q] = hp[(size_t)idx[q] * 96 + tb];
        #pragma unroll
        for (int q = 0; q < 8; ++q) {
            float2 p;
            p = unpkh(v[q].x); a0 += w[q] * p.x; a1 += w[q] * p.y;
            p = unpkh(v[q].y); a2 += w[q] * p.x; a3 += w[q] * p.y;
        }
    }
    for (; j + 4 <= e1; j += 4) {
        int i0 = cs[j], i1 = cs[j + 1], i2 = cs[j + 2], i3 = cs[j + 3];
        float w0 = wc[(size_t)(j + 0) * 3 + hd];
        float w1 = wc[(size_t)(j + 1) * 3 + hd];
        float w2 = wc[(size_t)(j + 2) * 3 + hd];
        float w3 = wc[(size_t)(j + 3) * 3 + hd];
        uint2 v0 = hp[(size_t)i0 * 96 + tb];
        uint2 v1 = hp[(size_t)i1 * 96 + tb];
        uint2 v2 = hp[(size_t)i2 * 96 + tb];
        uint2 v3 = hp[(size_t)i3 * 96 + tb];
        float2 p;
        p = unpkh(v0.x); a0 += w0 * p.x; a1 += w0 * p.y;
        p = unpkh(v0.y); a2 += w0 * p.x; a3 += w0 * p.y;
        p = unpkh(v1.x); a0 += w1 * p.x; a1 += w1 * p.y;
        p = unpkh(v1.y); a2 += w1 * p.x; a3 += w1 * p.y;
        p = unpkh(v2.x); a0 += w2 * p.x; a1 += w2 * p.y;
        p = unpkh(v2.y); a2 += w2 * p.x; a3 += w2 * p.y;
        p = unpkh(v3.x); a0 += w3 * p.x; a1 += w3 * p.y;
        p = unpkh(v3.y); a2 += w3 * p.x; a3 += w3 * p.y;
    }
    for (; j < e1; ++j) {
        int s = cs[j];
        float w = wc[(size_t)j * 3 + hd];
        uint2 v = hp[(size_t)s * 96 + tb];
        float2 p;
        p = unpkh(v.x); a0 += w * p.x; a1 += w * p.y;
        p = unpkh(v.y); a2 += w * p.x; a3 += w * p.y;
    }
    __shared__ float red[768];                    // br*384 + mt*192 + c
    int rb = br * 384 + mt * 192 + c;
    red[rb] = a0; red[rb + 1] = a1; red[rb + 2] = a2; red[rb + 3] = a3;
    __syncthreads();
    if (t < 128) {
        #pragma unroll
        for (int q = 0; q < 2; ++q) {
            int o = t + q * 128;                  // 0..255
            int obr = o >> 7, omt = (o >> 6) & 1, dd = o & 63;
            int base = obr * 384 + omt * 192;
            float tot = red[base + dd] + red[base + 64 + dd] + red[base + 128 + dd];
            const float* bias = omt ? blv : bmu;
            float v = tot * (1.f / 3.f) + bias[obr * 64 + dd];
            mt_gat[((size_t)(obr * 2 + omt) * NN + d) * 64 + dd] = v;
        }
    }
}

// ---------------- finalize: bias, z, 4-way max, outputs + split-fp16 z2 -------------
__global__ void k_finalize(const float* __restrict__ muv_gcn, const float* __restrict__ gcn_bmu,
                           const float* __restrict__ gcn_blv, const float* __restrict__ mt_gat,
                           const float* __restrict__ eps_gcn, const float* __restrict__ eps_gat,
                           float* __restrict__ mu_o, float* __restrict__ lv_o,
                           unsigned short* __restrict__ z2) {
    int i = blockIdx.x * 256 + threadIdx.x;       // NN*64
    int d = i >> 6, c = i & 63;
    const size_t NN64 = (size_t)NN * 64;
    float mu, lv, zm;
    {
        float m = muv_gcn[(size_t)d * 128 + c] + gcn_bmu[c];
        float l = muv_gcn[(size_t)d * 128 + 64 + c] + gcn_blv[c];
        float z = m + eps_gcn[i] * __expf(l);
        mu = m; lv = l; zm = z;
    }
    {
        float m = muv_gcn[NN64 * 2 + (size_t)d * 128 + c] + gcn_bmu[64 + c];
        float l = muv_gcn[NN64 * 2 + (size_t)d * 128 + 64 + c] + gcn_blv[64 + c];
        float z = m + eps_gcn[NN64 + i] * __expf(l);
        mu = fmaxf(mu, m); lv = fmaxf(lv, l); zm = fmaxf(zm, z);
    }
    #pragma unroll
    for (int br = 0; br < 2; ++br) {
        float m = mt_gat[(size_t)(br * 2 + 0) * NN64 + i];
        float l = mt_gat[(size_t)(br * 2 + 1) * NN64 + i];
        float z = m + eps_gat[(size_t)br * NN64 + i] * __expf(l);
        mu = fmaxf(mu, m); lv = fmaxf(lv, l); zm = fmaxf(zm, z);
    }
    mu_o[i] = mu;
    lv_o[i] = lv;
    unsigned short hh, ll;
    splith(zm, hh, ll);
    z2[(size_t)d * 128 + c] = hh;
    z2[(size_t)d * 128 + 64 + c] = ll;
}

extern "C" void kernel_launch(void* const* d_in, const int* in_sizes, int n_in,
                              void* d_out, int out_size, void* d_ws, size_t ws_size,
                              hipStream_t stream) {
    const float* x  = (const float*)d_in[0];
    const int*   ei = (const int*)d_in[1];
    const int E = in_sizes[1] / 2;
    const int E3 = E * 3;
    const int* src = ei;
    const int* dst = ei + E;

    const float* gcn_W1  = (const float*)d_in[2];
    const float* gcn_b1  = (const float*)d_in[3];
    const float* gcn_Wmu = (const float*)d_in[4];
    const float* gcn_bmu = (const float*)d_in[5];
    const float* gcn_Wlv = (const float*)d_in[6];
    const float* gcn_blv = (const float*)d_in[7];
    const float* gat_W1  = (const float*)d_in[8];
    const float* gat_as1 = (const float*)d_in[9];
    const float* gat_ad1 = (const float*)d_in[10];
    const float* gat_b1  = (const float*)d_in[11];
    const float* gat_Wmu = (const float*)d_in[12];
    const float* gat_asmu= (const float*)d_in[13];
    const float* gat_admu= (const float*)d_in[14];
    const float* gat_bmu = (const float*)d_in[15];
    const float* gat_Wlv = (const float*)d_in[16];
    const float* gat_aslv= (const float*)d_in[17];
    const float* gat_adlv= (const float*)d_in[18];
    const float* gat_blv = (const float*)d_in[19];
    const float* eps_gcn = (const float*)d_in[20];
    const float* eps_gat = (const float*)d_in[21];

    // ---- workspace carve ----
    char* p = (char*)d_ws;
    auto alloc = [&](size_t bytes) {
        void* r = (void*)p;
        p += (bytes + 255) & ~(size_t)255;
        return r;
    };
    int*   cnt     = (int*)alloc((size_t)NN * 4);
    int*   cursor  = (int*)alloc((size_t)NN * 4);       // contiguous after cnt
    int*   row_ptr = (int*)alloc((size_t)(NN + 1) * 4);
    int*   csr_src = (int*)alloc((size_t)E * 4);
    float* dinv    = (float*)alloc((size_t)NN * 4);
    float* as_n1   = (float*)alloc((size_t)2 * NN * 3 * 4);
    float* ad_n1   = (float*)alloc((size_t)2 * NN * 3 * 4);
    float* wself1  = (float*)alloc((size_t)2 * NN * 3 * 4);
    float* wcsr1   = (float*)alloc((size_t)2 * E3 * 4);
    float* as_n2   = (float*)alloc((size_t)4 * NN * 3 * 4);
    float* ad_n2   = (float*)alloc((size_t)4 * NN * 3 * 4);
    float* wself2  = (float*)alloc((size_t)4 * NN * 3 * 4);
    float* wcsr2   = (float*)alloc((size_t)4 * E3 * 4);
    unsigned short* x2h      = (unsigned short*)alloc((size_t)NN * 512 * 2);
    unsigned short* wt_gcn1  = (unsigned short*)alloc((size_t)256 * 512 * 2);
    unsigned short* wt_gcnmuv= (unsigned short*)alloc((size_t)2 * 128 * 128 * 2);
    unsigned short* wt_gat1  = (unsigned short*)alloc((size_t)768 * 512 * 2);
    unsigned short* wt_gatmuv= (unsigned short*)alloc((size_t)2 * 384 * 384 * 2);
    unsigned short* xwb  = (unsigned short*)alloc((size_t)NN * 768 * 2);  // GCN uses ld 256
    unsigned short* hb   = (unsigned short*)alloc((size_t)NN * 256 * 2);
    unsigned short* hA   = (unsigned short*)alloc((size_t)NN * 256 * 2);
    float* muv_gcn = (float*)alloc((size_t)2 * NN * 128 * 4);
    unsigned short* h1s  = (unsigned short*)alloc((size_t)NN * 768 * 2);
    unsigned short* h2gb = (unsigned short*)alloc((size_t)2 * NN * 384 * 2);
    float* mt_gat  = (float*)alloc((size_t)4 * NN * 64 * 4);
    unsigned short* z2 = (unsigned short*)alloc((size_t)NN * 128 * 2);

    float* adj  = (float*)d_out;
    float* mu_o = adj + (size_t)NN * NN;
    float* lv_o = mu_o + (size_t)NN * 64;

    // ---- CSR build ----
    hipMemsetAsync(cnt, 0, (size_t)2 * NN * 4, stream);   // cnt + cursor
    k_count<<<(E + 255) / 256, 256, 0, stream>>>(dst, cnt, E);
    k_scan<<<1, 1024, 0, stream>>>(cnt, row_ptr, dinv);
    k_fill<<<(E + 255) / 256, 256, 0, stream>>>(src, dst, row_ptr, cursor, csr_src, E);

    // ---- precision prep (fp16) ----
    k_cvt_x<<<NN * 512 / 4 / 256, 256, 0, stream>>>(x, x2h);
    k_wT<<<dim3(16, 4, 2), 256, 0, stream>>>(gcn_W1, wt_gcn1, 512, 128, 0, 0, 128);
    k_wT2<<<dim3(4, 2, 4), 256, 0, stream>>>(gcn_Wmu, gcn_Wlv, wt_gcnmuv, 128, 64,
                                             (size_t)128 * 128, 64);
    k_wT<<<dim3(16, 12, 2), 256, 0, stream>>>(gat_W1, wt_gat1, 512, 384, 0, 0, 384);
    k_wT2<<<dim3(12, 6, 4), 256, 0, stream>>>(gat_Wmu, gat_Wlv, wt_gatmuv, 384, 192,
                                              (size_t)384 * 384, 192);

    // ---- GCN (both branches batched) ----
    // g1: xwb[:, :256] = fp16(x2h @ wt_gcn1)  (K=512, N=256), ldc=256
    k_gemm2<1, 2><<<dim3(64, 4, 1), 256, 0, stream>>>(x2h, 0, 512, wt_gcn1, 0, 512,
                                                      xwb, 0, 256, 512);
    k_gcn_a1<<<NN, 64, 0, stream>>>((const uint2*)xwb, dinv, row_ptr, csr_src, gcn_b1,
                                    (uint2*)hb);
    k_gcn_a2<<<NN, 64, 0, stream>>>((const uint2*)hb, dinv, row_ptr, csr_src, (uint2*)hA);
    // g2: muv[z] = hA[z] @ wt_gcnmuv[z]  (K=128, N=128), fp32 out
    k_gemm2<1, 0><<<dim3(64, 2, 2), 256, 0, stream>>>(hA, 128, 256, wt_gcnmuv,
                                                      (size_t)128 * 128, 128,
                                                      muv_gcn, (size_t)NN * 128, 128, 128);

    // ---- GAT (both branches batched) ----
    // G1: xwb = fp16(x2h @ wt_gat1)  (K=512, N=768)
    k_gemm2<1, 2><<<dim3(64, 12, 1), 256, 0, stream>>>(x2h, 0, 512, wt_gat1, 0, 512,
                                                       xwb, 0, 768, 512);
    k_gat_log1<<<dim3(NN, 1, 2), 192, 0, stream>>>((const unsigned int*)xwb, gat_as1,
                                                   gat_ad1, as_n1, ad_n1);
    k_gat_attn<<<dim3(NN, 1, 2), 192, 0, stream>>>(as_n1, ad_n1, row_ptr, csr_src,
                                                   wcsr1, wself1, E3);
    k_gat_agg1<<<NN, 192, 0, stream>>>((const uint2*)xwb, wcsr1, wself1, row_ptr, csr_src,
                                       gat_b1, (uint2*)h1s, E3);
    // G2: h2gb[z] = fp16(h1s[z] @ wt_gatmuv[z])  (K=384, N=384)
    k_gemm2<1, 2><<<dim3(64, 6, 2), 256, 0, stream>>>(h1s, 384, 768, wt_gatmuv,
                                                      (size_t)384 * 384, 384,
                                                      h2gb, (size_t)NN * 384, 384, 384);
    k_gat_log2<<<dim3(NN, 1, 4), 192, 0, stream>>>(h2gb, gat_asmu, gat_aslv, gat_admu,
                                                   gat_adlv, as_n2, ad_n2);
    k_gat_attn<<<dim3(NN, 1, 4), 192, 0, stream>>>(as_n2, ad_n2, row_ptr, csr_src,
                                                   wcsr2, wself2, E3);
    k_gat_agg2<<<NN, 192, 0, stream>>>((const uint2*)h2gb, wcsr2, wself2, row_ptr, csr_src,
                                       gat_bmu, gat_blv, mt_gat, E3);

    // ---- finalize + adjacency (fp16 hi/lo 2-term) ----
    k_finalize<<<NN * 64 / 256, 256, 0, stream>>>(muv_gcn, gcn_bmu, gcn_blv, mt_gat,
                                                  eps_gcn, eps_gat, mu_o, lv_o, z2);
    k_gemm2<2, 1><<<dim3(64, 128, 1), 256, 0, stream>>>(z2, 0, 128, z2, 0, 128,
                                                        adj, 0, NN, 64);
}

// Round 14
// 344.426 us; speedup vs baseline: 1.1451x; 1.0210x over previous
//
#include <hip/hip_runtime.h>
#include <hip/hip_bf16.h>
#include <math.h>
#include <stddef.h>

#define NN 8192
#define NEG_SLOPE 0.2f

typedef _Float16 h8 __attribute__((ext_vector_type(8)));
typedef __attribute__((ext_vector_type(4))) float f32x4;

__device__ __forceinline__ float lrelu(float x) { return x > 0.f ? x : NEG_SLOPE * x; }
__device__ __forceinline__ float sigf(float x) { return 1.f / (1.f + __expf(-x)); }

__device__ __forceinline__ unsigned short f16b(float x) {
    _Float16 h = (_Float16)x;
    unsigned short u;
    __builtin_memcpy(&u, &h, 2);
    return u;
}
__device__ __forceinline__ float f16f(unsigned short u) {
    _Float16 h;
    __builtin_memcpy(&h, &u, 2);
    return (float)h;
}
__device__ __forceinline__ void splith(float x, unsigned short& hu, unsigned short& lu) {
    _Float16 h = (_Float16)x;
    float hf = (float)h;
    _Float16 l = (_Float16)(x - hf);
    __builtin_memcpy(&hu, &h, 2);
    __builtin_memcpy(&lu, &l, 2);
}
__device__ __forceinline__ float2 unpkh(unsigned int v) {
    float2 r;
    r.x = f16f((unsigned short)(v & 0xffffu));
    r.y = f16f((unsigned short)(v >> 16));
    return r;
}
__device__ __forceinline__ unsigned int packh(float a, float b) {
    return (unsigned int)f16b(a) | ((unsigned int)f16b(b) << 16);
}

// async global->LDS, 16B per lane; lds base must be wave-uniform
__device__ __forceinline__ void gll16(const unsigned short* g, unsigned short* l) {
    __builtin_amdgcn_global_load_lds(
        (const __attribute__((address_space(1))) unsigned int*)g,
        (__attribute__((address_space(3))) unsigned int*)l, 16, 0, 0);
}

// ---------------- CSR build ----------------
__global__ void k_count(const int* __restrict__ dst, int* __restrict__ cnt, int E) {
    int i = blockIdx.x * blockDim.x + threadIdx.x;
    if (i < E) atomicAdd(&cnt[dst[i]], 1);
}
// scan + dinv fused
__global__ void k_scan(const int* __restrict__ cnt, int* __restrict__ row_ptr,
                       float* __restrict__ dinv) {
    __shared__ int part[1024];
    int t = threadIdx.x;
    int base = t * 8;
    int loc[8];
    int s = 0;
    #pragma unroll
    for (int j = 0; j < 8; ++j) {
        int cv = cnt[base + j];
        loc[j] = s;
        s += cv;
        dinv[base + j] = rsqrtf((float)(cv + 1));
    }
    part[t] = s;
    __syncthreads();
    for (int off = 1; off < 1024; off <<= 1) {
        int v = (t >= off) ? part[t - off] : 0;
        __syncthreads();
        part[t] += v;
        __syncthreads();
    }
    int pre = (t == 0) ? 0 : part[t - 1];
    #pragma unroll
    for (int j = 0; j < 8; ++j) row_ptr[base + j] = pre + loc[j];
    if (t == 1023) row_ptr[NN] = part[1023];
}
__global__ void k_fill(const int* __restrict__ src, const int* __restrict__ dst,
                       const int* __restrict__ row_ptr, int* __restrict__ cursor,
                       int* __restrict__ csr_src, int E) {
    int i = blockIdx.x * blockDim.x + threadIdx.x;
    if (i < E) {
        int d = dst[i];
        csr_src[row_ptr[d] + atomicAdd(&cursor[d], 1)] = src[i];
    }
}

// ---------------- x fp32 -> fp16 ----------------
__global__ void k_cvt_x(const float* __restrict__ x, unsigned short* __restrict__ xh) {
    int i = blockIdx.x * 256 + threadIdx.x;     // over NN*512/4
    int m = i >> 7, k4 = (i & 127) * 4;
    float4 v = *(const float4*)(x + (size_t)m * 512 + k4);
    ushort4 o;
    o.x = f16b(v.x); o.y = f16b(v.y); o.z = f16b(v.z); o.w = f16b(v.w);
    *(ushort4*)&xh[(size_t)m * 512 + k4] = o;
}

// W [K,N] fp32 -> Wt fp16 rows (noff + b*noff_z + n) of length K
__global__ void k_wT(const float* __restrict__ W, unsigned short* __restrict__ Wt,
                     int K, int N, size_t wt_z_stride, int noff, int noff_z) {
    int b = blockIdx.z;
    W += (size_t)b * K * N;
    Wt += (size_t)b * wt_z_stride;
    int rowbase = noff + b * noff_z;
    int k0 = blockIdx.x * 32, n0 = blockIdx.y * 32;
    __shared__ float tl[32][33];
    int tid = threadIdx.x;
    int r = tid >> 5, cc = tid & 31;
    #pragma unroll
    for (int c = 0; c < 4; ++c)
        tl[r + c * 8][cc] = W[(size_t)(k0 + r + c * 8) * N + n0 + cc];
    __syncthreads();
    #pragma unroll
    for (int c = 0; c < 4; ++c) {
        int n = r + c * 8, k = cc;
        Wt[(size_t)(rowbase + n0 + n) * K + k0 + k] = f16b(tl[k][n]);
    }
}

// merged mu/lv transpose: z = mt*2 + br; lv rows offset by lv_rowoff
__global__ void k_wT2(const float* __restrict__ Wmu, const float* __restrict__ Wlv,
                      unsigned short* __restrict__ Wt, int K, int N,
                      size_t wt_br_stride, int lv_rowoff) {
    int z = blockIdx.z;
    int mt = z >> 1, b = z & 1;
    const float* W = (mt ? Wlv : Wmu) + (size_t)b * K * N;
    Wt += (size_t)b * wt_br_stride;
    int rowbase = mt ? lv_rowoff : 0;
    int k0 = blockIdx.x * 32, n0 = blockIdx.y * 32;
    __shared__ float tl[32][33];
    int tid = threadIdx.x;
    int r = tid >> 5, cc = tid & 31;
    #pragma unroll
    for (int c = 0; c < 4; ++c)
        tl[r + c * 8][cc] = W[(size_t)(k0 + r + c * 8) * N + n0 + cc];
    __syncthreads();
    #pragma unroll
    for (int c = 0; c < 4; ++c) {
        int n = r + c * 8, k = cc;
        Wt[(size_t)(rowbase + n0 + n) * K + k0 + k] = f16b(tl[k][n]);
    }
}

// ---------------- fp16 MFMA GEMM, 512 threads, BM=128 BN=128 BK=64 ----------------
// 8 waves (2 rows x 4 cols of 64x32 sub-tiles). stage: 128 rows x 64 cols per tile.
__device__ __forceinline__ void stage8(const unsigned short* __restrict__ gbase, int lda,
                                       unsigned short* lds, int wid, int lane) {
    #pragma unroll
    for (int c = 0; c < 2; ++c) {
        int chunk = c * 8 + wid;                // 16 x 1KB chunks (8 rows each)
        int row = chunk * 8 + (lane >> 3);
        int g = (lane & 7) ^ (row & 7);
        gll16(gbase + (size_t)row * lda + g * 8, lds + chunk * 512);
    }
}
__device__ __forceinline__ h8 fragrh(const unsigned short* lds, int row, int kg) {
    return *(const h8*)(lds + row * 64 + ((kg ^ (row & 7)) * 8));
}

// TERMS: 1 = Ah*Bh; 2 = (Ah+Al)*Bh
template <int TERMS, int EPI>   // EPI: 0 fp32, 1 fp32+sigmoid, 2 fp16
__global__ __launch_bounds__(512) void k_gemm2(
    const unsigned short* __restrict__ A2, size_t azs, int lda,
    const unsigned short* __restrict__ B2, size_t bzs, int ldb,
    void* __restrict__ Cv, size_t czs, int ldc, int K) {
    __shared__ __align__(16) unsigned short sAh[128 * 64];
    __shared__ __align__(16) unsigned short sBh[128 * 64];
    __shared__ __align__(16) unsigned short sAl[(TERMS >= 2) ? 128 * 64 : 8];
    const int tid = threadIdx.x;
    const int wid = tid >> 6, lane = tid & 63;
    const int wr = wid >> 2, wc = wid & 3;
    const int lr = lane & 15, lg = lane >> 4;
    const int m0 = blockIdx.x * 128, n0 = blockIdx.y * 128;
    const int z = blockIdx.z;
    A2 += (size_t)z * azs;
    B2 += (size_t)z * bzs;

    const f32x4 zero4 = {0.f, 0.f, 0.f, 0.f};
    f32x4 acc[4][2];
    #pragma unroll
    for (int m = 0; m < 4; ++m)
        #pragma unroll
        for (int n = 0; n < 2; ++n) acc[m][n] = zero4;

    for (int k0 = 0; k0 < K; k0 += 64) {
        stage8(A2 + (size_t)m0 * lda + k0, lda, sAh, wid, lane);
        stage8(B2 + (size_t)n0 * ldb + k0, ldb, sBh, wid, lane);
        if (TERMS >= 2) stage8(A2 + (size_t)m0 * lda + K + k0, lda, sAl, wid, lane);
        __syncthreads();
        #pragma unroll
        for (int ks = 0; ks < 2; ++ks) {
            const int kg = ks * 4 + lg;
            h8 ah[4], al[4], bh[2];
            #pragma unroll
            for (int m = 0; m < 4; ++m) {
                int row = wr * 64 + m * 16 + lr;
                ah[m] = fragrh(sAh, row, kg);
                if (TERMS >= 2) al[m] = fragrh(sAl, row, kg);
            }
            #pragma unroll
            for (int n = 0; n < 2; ++n) {
                int row = wc * 32 + n * 16 + lr;
                bh[n] = fragrh(sBh, row, kg);
            }
            #pragma unroll
            for (int m = 0; m < 4; ++m)
                #pragma unroll
                for (int n = 0; n < 2; ++n) {
                    acc[m][n] = __builtin_amdgcn_mfma_f32_16x16x32_f16(ah[m], bh[n], acc[m][n], 0, 0, 0);
                    if (TERMS >= 2)
                        acc[m][n] = __builtin_amdgcn_mfma_f32_16x16x32_f16(al[m], bh[n], acc[m][n], 0, 0, 0);
                }
        }
        __syncthreads();
    }
    #pragma unroll
    for (int m = 0; m < 4; ++m)
        #pragma unroll
        for (int n = 0; n < 2; ++n)
            #pragma unroll
            for (int j = 0; j < 4; ++j) {
                int row = m0 + wr * 64 + m * 16 + lg * 4 + j;
                int col = n0 + wc * 32 + n * 16 + lr;
                float o = acc[m][n][j];
                if (EPI == 1) {
                    ((float*)Cv + (size_t)z * czs)[(size_t)row * ldc + col] = sigf(o);
                } else if (EPI == 2) {
                    ((unsigned short*)Cv + (size_t)z * czs)[(size_t)row * ldc + col] = f16b(o);
                } else {
                    ((float*)Cv + (size_t)z * czs)[(size_t)row * ldc + col] = o;
                }
            }
}

// ---------------- GCN layer1 aggregate: reads xw_all cols 0..255 (ld 256 uint2) -----
__global__ void k_gcn_a1(const uint2* __restrict__ xw2, const float* __restrict__ dinv,
                         const int* __restrict__ rp, const int* __restrict__ cs,
                         const float* __restrict__ b1, uint2* __restrict__ hb2) {
    int d = blockIdx.x;
    int t = threadIdx.x;                         // 64 uint2 cols (256 fp)
    float dd = dinv[d];
    uint2 sv = xw2[(size_t)d * 256 + t];
    float2 s0 = unpkh(sv.x), s1 = unpkh(sv.y);
    float a0 = dd * s0.x, a1 = dd * s0.y, a2 = dd * s1.x, a3 = dd * s1.y;
    int e0 = rp[d], e1 = rp[d + 1];
    int j = e0;
    for (; j + 8 <= e1; j += 8) {
        int idx[8]; float w[8]; uint2 v[8];
        #pragma unroll
        for (int q = 0; q < 8; ++q) idx[q] = cs[j + q];
        #pragma unroll
        for (int q = 0; q < 8; ++q) w[q] = dinv[idx[q]];
        #pragma unroll
        for (int q = 0; q < 8; ++q) v[q] = xw2[(size_t)idx[q] * 256 + t];
        #pragma unroll
        for (int q = 0; q < 8; ++q) {
            float2 p;
            p = unpkh(v[q].x); a0 += w[q] * p.x; a1 += w[q] * p.y;
            p = unpkh(v[q].y); a2 += w[q] * p.x; a3 += w[q] * p.y;
        }
    }
    for (; j + 4 <= e1; j += 4) {
        int i0 = cs[j], i1 = cs[j + 1], i2 = cs[j + 2], i3 = cs[j + 3];
        float w0 = dinv[i0], w1 = dinv[i1], w2 = dinv[i2], w3 = dinv[i3];
        uint2 v0 = xw2[(size_t)i0 * 256 + t];
        uint2 v1 = xw2[(size_t)i1 * 256 + t];
        uint2 v2 = xw2[(size_t)i2 * 256 + t];
        uint2 v3 = xw2[(size_t)i3 * 256 + t];
        float2 p;
        p = unpkh(v0.x); a0 += w0 * p.x; a1 += w0 * p.y;
        p = unpkh(v0.y); a2 += w0 * p.x; a3 += w0 * p.y;
        p = unpkh(v1.x); a0 += w1 * p.x; a1 += w1 * p.y;
        p = unpkh(v1.y); a2 += w1 * p.x; a3 += w1 * p.y;
        p = unpkh(v2.x); a0 += w2 * p.x; a1 += w2 * p.y;
        p = unpkh(v2.y); a2 += w2 * p.x; a3 += w2 * p.y;
        p = unpkh(v3.x); a0 += w3 * p.x; a1 += w3 * p.y;
        p = unpkh(v3.y); a2 += w3 * p.x; a3 += w3 * p.y;
    }
    for (; j < e1; ++j) {
        int s = cs[j];
        float w = dinv[s];
        uint2 v = xw2[(size_t)s * 256 + t];
        float2 p;
        p = unpkh(v.x); a0 += w * p.x; a1 += w * p.y;
        p = unpkh(v.y); a2 += w * p.x; a3 += w * p.y;
    }
    int c = 4 * t;
    float o0 = fmaxf(dd * a0 + b1[c], 0.f);
    float o1 = fmaxf(dd * a1 + b1[c + 1], 0.f);
    float o2 = fmaxf(dd * a2 + b1[c + 2], 0.f);
    float o3 = fmaxf(dd * a3 + b1[c + 3], 0.f);
    uint2 o;
    o.x = packh(o0, o1);
    o.y = packh(o2, o3);
    hb2[(size_t)d * 64 + t] = o;
}

// ---------------- GCN second aggregate: hA = Agg(h) fp16, 64 thr x uint2 ------------
__global__ void k_gcn_a2(const uint2* __restrict__ hb2, const float* __restrict__ dinv,
                         const int* __restrict__ rp, const int* __restrict__ cs,
                         uint2* __restrict__ hA2) {
    int d = blockIdx.x;
    int t = threadIdx.x;                         // 64 uint2 cols
    float dd = dinv[d];
    uint2 sv = hb2[(size_t)d * 64 + t];
    float2 s0 = unpkh(sv.x), s1 = unpkh(sv.y);
    float a0 = dd * s0.x, a1 = dd * s0.y, a2 = dd * s1.x, a3 = dd * s1.y;
    int e0 = rp[d], e1 = rp[d + 1];
    int j = e0;
    for (; j + 8 <= e1; j += 8) {
        int idx[8]; float w[8]; uint2 v[8];
        #pragma unroll
        for (int q = 0; q < 8; ++q) idx[q] = cs[j + q];
        #pragma unroll
        for (int q = 0; q < 8; ++q) w[q] = dinv[idx[q]];
        #pragma unroll
        for (int q = 0; q < 8; ++q) v[q] = hb2[(size_t)idx[q] * 64 + t];
        #pragma unroll
        for (int q = 0; q < 8; ++q) {
            float2 p;
            p = unpkh(v[q].x); a0 += w[q] * p.x; a1 += w[q] * p.y;
            p = unpkh(v[q].y); a2 += w[q] * p.x; a3 += w[q] * p.y;
        }
    }
    for (; j + 4 <= e1; j += 4) {
        int i0 = cs[j], i1 = cs[j + 1], i2 = cs[j + 2], i3 = cs[j + 3];
        float w0 = dinv[i0], w1 = dinv[i1], w2 = dinv[i2], w3 = dinv[i3];
        uint2 v0 = hb2[(size_t)i0 * 64 + t];
        uint2 v1 = hb2[(size_t)i1 * 64 + t];
        uint2 v2 = hb2[(size_t)i2 * 64 + t];
        uint2 v3 = hb2[(size_t)i3 * 64 + t];
        float2 p;
        p = unpkh(v0.x); a0 += w0 * p.x; a1 += w0 * p.y;
        p = unpkh(v0.y); a2 += w0 * p.x; a3 += w0 * p.y;
        p = unpkh(v1.x); a0 += w1 * p.x; a1 += w1 * p.y;
        p = unpkh(v1.y); a2 += w1 * p.x; a3 += w1 * p.y;
        p = unpkh(v2.x); a0 += w2 * p.x; a1 += w2 * p.y;
        p = unpkh(v2.y); a2 += w2 * p.x; a3 += w2 * p.y;
        p = unpkh(v3.x); a0 += w3 * p.x; a1 += w3 * p.y;
        p = unpkh(v3.y); a2 += w3 * p.x; a3 += w3 * p.y;
    }
    for (; j < e1; ++j) {
        int s = cs[j];
        float w = dinv[s];
        uint2 v = hb2[(size_t)s * 64 + t];
        float2 p;
        p = unpkh(v.x); a0 += w * p.x; a1 += w * p.y;
        p = unpkh(v.y); a2 += w * p.x; a3 += w * p.y;
    }
    uint2 o;
    o.x = packh(dd * a0, dd * a1);
    o.y = packh(dd * a2, dd * a3);
    hA2[(size_t)d * 64 + t] = o;
}

// ---------------- GAT layer1 logits from xw_all (uints, +128 offset) ----------------
__global__ void k_gat_log1(const unsigned int* __restrict__ xwu, const float* __restrict__ a_s,
                           const float* __restrict__ a_d, float* __restrict__ as_n,
                           float* __restrict__ ad_n) {
    int br = blockIdx.z;
    int n = blockIdx.x;
    int hd = threadIdx.x >> 6, lane = threadIdx.x & 63;   // block 192
    const unsigned int* hp = xwu + (size_t)n * 512 + 128 + br * 192 + hd * 64;
    const float* av = a_s + br * 384 + hd * 128;
    const float* dv = a_d + br * 384 + hd * 128;
    float2 f = unpkh(hp[lane]);
    float ss = f.x * av[2 * lane] + f.y * av[2 * lane + 1];
    float sd = f.x * dv[2 * lane] + f.y * dv[2 * lane + 1];
    #pragma unroll
    for (int off = 32; off; off >>= 1) {
        ss += __shfl_down(ss, off);
        sd += __shfl_down(sd, off);
    }
    if (lane == 0) {
        as_n[(size_t)br * NN * 3 + n * 3 + hd] = ss;
        ad_n[(size_t)br * NN * 3 + n * 3 + hd] = sd;
    }
}

// ---------------- GAT layer2 logits (z = branch*2 + mtype) ----------------
__global__ void k_gat_log2(const unsigned short* __restrict__ h2gb, const float* __restrict__ asmu,
                           const float* __restrict__ aslv, const float* __restrict__ admu,
                           const float* __restrict__ adlv, float* __restrict__ as_n,
                           float* __restrict__ ad_n) {
    int zz = blockIdx.z;
    int br = zz >> 1, mt = zz & 1;
    int n = blockIdx.x;
    int hd = threadIdx.x >> 6, lane = threadIdx.x & 63;   // block 192
    const unsigned short* hp = h2gb + (size_t)br * NN * 384 + (size_t)n * 384 + mt * 192 + hd * 64;
    const float* av = (mt ? aslv : asmu) + br * 192 + hd * 64;
    const float* dv = (mt ? adlv : admu) + br * 192 + hd * 64;
    float hv = f16f(hp[lane]);
    float ss = hv * av[lane];
    float sd = hv * dv[lane];
    #pragma unroll
    for (int off = 32; off; off >>= 1) {
        ss += __shfl_down(ss, off);
        sd += __shfl_down(sd, off);
    }
    if (lane == 0) {
        as_n[(size_t)zz * NN * 3 + n * 3 + hd] = ss;
        ad_n[(size_t)zz * NN * 3 + n * 3 + hd] = sd;
    }
}

// ---------------- GAT softmax weights (z batched, wave per head) ----------------
__global__ void k_gat_attn(const float* __restrict__ as_n, const float* __restrict__ ad_n,
                           const int* __restrict__ rp, const int* __restrict__ cs,
                           float* __restrict__ w_csr, float* __restrict__ w_self, int E3) {
    int zz = blockIdx.z;
    as_n += (size_t)zz * NN * 3;
    ad_n += (size_t)zz * NN * 3;
    w_csr += (size_t)zz * E3;
    w_self += (size_t)zz * NN * 3;
    int d = blockIdx.x;
    int hd = threadIdx.x >> 6, lane = threadIdx.x & 63;   // block 192
    int e0 = rp[d], e1 = rp[d + 1];
    float add = ad_n[d * 3 + hd];
    float eself = lrelu(as_n[d * 3 + hd] + add);
    float mx = eself;
    for (int j = e0 + lane; j < e1; j += 64) {
        float e = lrelu(as_n[cs[j] * 3 + hd] + add);
        w_csr[(size_t)j * 3 + hd] = e;
        mx = fmaxf(mx, e);
    }
    #pragma unroll
    for (int off = 32; off; off >>= 1) mx = fmaxf(mx, __shfl_xor(mx, off));
    float sm = (lane == 0) ? __expf(eself - mx) : 0.f;
    for (int j = e0 + lane; j < e1; j += 64)
        sm += __expf(w_csr[(size_t)j * 3 + hd] - mx);
    #pragma unroll
    for (int off = 32; off; off >>= 1) sm += __shfl_xor(sm, off);
    float inv = 1.f / sm;
    if (lane == 0) w_self[d * 3 + hd] = __expf(eself - mx) * inv;
    for (int j = e0 + lane; j < e1; j += 64)
        w_csr[(size_t)j * 3 + hd] = __expf(w_csr[(size_t)j * 3 + hd] - mx) * inv;
}

// ---------------- GAT layer1 aggregate from xw_all (+64 uint2 offset, ld 256) -------
__global__ void k_gat_agg1(const uint2* __restrict__ xw2, const float* __restrict__ w_csr,
                           const float* __restrict__ w_self, const int* __restrict__ rp,
                           const int* __restrict__ cs, const float* __restrict__ b1,
                           uint2* __restrict__ h1s2, int E3) {
    int d = blockIdx.x;
    int t = threadIdx.x;                          // 192 uint2 cols (768 fp)
    int br = t >= 96 ? 1 : 0;
    int c = 4 * t - br * 384;                     // fp col within branch
    int hd = c >> 7;
    const float* wc = w_csr + (size_t)br * E3;
    float ws = w_self[(size_t)br * NN * 3 + d * 3 + hd];
    uint2 sv = xw2[(size_t)d * 256 + 64 + t];
    float2 s0 = unpkh(sv.x), s1 = unpkh(sv.y);
    float a0 = ws * s0.x, a1 = ws * s0.y, a2 = ws * s1.x, a3 = ws * s1.y;
    int e0 = rp[d], e1 = rp[d + 1];
    int j = e0;
    for (; j + 8 <= e1; j += 8) {
        int idx[8]; float w[8]; uint2 v[8];
        #pragma unroll
        for (int q = 0; q < 8; ++q) idx[q] = cs[j + q];
        #pragma unroll
        for (int q = 0; q < 8; ++q) w[q] = wc[(size_t)(j + q) * 3 + hd];
        #pragma unroll
        for (int q = 0; q < 8; ++q) v[q] = xw2[(size_t)idx[q] * 256 + 64 + t];
        #pragma unroll
        for (int q = 0; q < 8; ++q) {
            float2 p;
            p = unpkh(v[q].x); a0 += w[q] * p.x; a1 += w[q] * p.y;
            p = unpkh(v[q].y); a2 += w[q] * p.x; a3 += w[q] * p.y;
        }
    }
    for (; j + 4 <= e1; j += 4) {
        int i0 = cs[j], i1 = cs[j + 1], i2 = cs[j + 2], i3 = cs[j + 3];
        float w0 = wc[(size_t)(j + 0) * 3 + hd];
        float w1 = wc[(size_t)(j + 1) * 3 + hd];
        float w2 = wc[(size_t)(j + 2) * 3 + hd];
        float w3 = wc[(size_t)(j + 3) * 3 + hd];
        uint2 v0 = xw2[(size_t)i0 * 256 + 64 + t];
        uint2 v1 = xw2[(size_t)i1 * 256 + 64 + t];
        uint2 v2 = xw2[(size_t)i2 * 256 + 64 + t];
        uint2 v3 = xw2[(size_t)i3 * 256 + 64 + t];
        float2 p;
        p = unpkh(v0.x); a0 += w0 * p.x; a1 += w0 * p.y;
        p = unpkh(v0.y); a2 += w0 * p.x; a3 += w0 * p.y;
        p = unpkh(v1.x); a0 += w1 * p.x; a1 += w1 * p.y;
        p = unpkh(v1.y); a2 += w1 * p.x; a3 += w1 * p.y;
        p = unpkh(v2.x); a0 += w2 * p.x; a1 += w2 * p.y;
        p = unpkh(v2.y); a2 += w2 * p.x; a3 += w2 * p.y;
        p = unpkh(v3.x); a0 += w3 * p.x; a1 += w3 * p.y;
        p = unpkh(v3.y); a2 += w3 * p.x; a3 += w3 * p.y;
    }
    for (; j < e1; ++j) {
        int s = cs[j];
        float w = wc[(size_t)j * 3 + hd];
        uint2 v = xw2[(size_t)s * 256 + 64 + t];
        float2 p;
        p = unpkh(v.x); a0 += w * p.x; a1 += w * p.y;
        p = unpkh(v.y); a2 += w * p.x; a3 += w * p.y;
    }
    int cg = 4 * t;                               // global fp col
    float o0 = fmaxf(a0 + b1[cg], 0.f);
    float o1 = fmaxf(a1 + b1[cg + 1], 0.f);
    float o2 = fmaxf(a2 + b1[cg + 2], 0.f);
    float o3 = fmaxf(a3 + b1[cg + 3], 0.f);
    uint2 o;
    o.x = packh(o0, o1);
    o.y = packh(o2, o3);
    h1s2[(size_t)d * 192 + t] = o;
}

// ---------------- GAT layer2 aggregate, both branches + mu/lv (192 thr) -------------
__global__ void k_gat_agg2(const uint2* __restrict__ h2g2, const float* __restrict__ w_csr,
                           const float* __restrict__ w_self, const int* __restrict__ rp,
                           const int* __restrict__ cs, const float* __restrict__ bmu,
                           const float* __restrict__ blv, float* __restrict__ mt_gat, int E3) {
    int d = blockIdx.x;
    int t = threadIdx.x;                          // 192: br(2) x 96 uint2 (384 fp each)
    int br = t >= 96 ? 1 : 0;
    int tb = t - br * 96;
    int mt = tb >= 48 ? 1 : 0;
    int c = 4 * tb - mt * 192;                    // fp col within (br,mt), 0..191
    int hd = c >> 6;
    const float* wc = w_csr + (size_t)(br * 2 + mt) * E3;
    float ws = w_self[(size_t)(br * 2 + mt) * NN * 3 + d * 3 + hd];
    const uint2* hp = h2g2 + (size_t)br * NN * 96;
    uint2 sv = hp[(size_t)d * 96 + tb];
    float2 s0 = unpkh(sv.x), s1 = unpkh(sv.y);
    float a0 = ws * s0.x, a1 = ws * s0.y, a2 = ws * s1.x, a3 = ws * s1.y;
    int e0 = rp[d], e1 = rp[d + 1];
    int j = e0;
    for (; j + 8 <= e1; j += 8) {
        int idx[8]; float w[8]; uint2 v[8];
        #pragma unroll
        for (int q = 0; q < 8; ++q) idx[q] = cs[j + q];
        #pragma unroll
        for (int q = 0; q < 8; ++q) w[q] = wc[(size_t)(j + q) * 3 + hd];
        #pragma unroll
        for (int q = 0; q < 8; ++q) v[q] = hp[(size_t)idx[q] * 96 + tb];
        #pragma unroll
        for (int q = 0; q < 8; ++q) {
            float2 p;
            p = unpkh(v[q].x); a0 += w[q] * p.x; a1 += w[q] * p.y;
            p = unpkh(v[q].y); a2 += w[q] * p.x; a3 += w[q] * p.y;
        }
    }
    for (; j + 4 <= e1; j += 4) {
        int i0 = cs[j], i1 = cs[j + 1], i2 = cs[j + 2], i3 = cs[j + 3];
        float w0 = wc[(size_t)(j + 0) * 3 + hd];
        float w1 = wc[(size_t)(j + 1) * 3 + hd];
        float w2 = wc[(size_t)(j + 2) * 3 + hd];
        float w3 = wc[(size_t)(j + 3) * 3 + hd];
        uint2 v0 = hp[(size_t)i0 * 96 + tb];
        uint2 v1 = hp[(size_t)i1 * 96 + tb];
        uint2 v2 = hp[(size_t)i2 * 96 + tb];
        uint2 v3 = hp[(size_t)i3 * 96 + tb];
        float2 p;
        p = unpkh(v0.x); a0 += w0 * p.x; a1 += w0 * p.y;
        p = unpkh(v0.y); a2 += w0 * p.x; a3 += w0 * p.y;
        p = unpkh(v1.x); a0 += w1 * p.x; a1 += w1 * p.y;
        p = unpkh(v1.y); a2 += w1 * p.x; a3 += w1 * p.y;
        p = unpkh(v2.x); a0 += w2 * p.x; a1 += w2 * p.y;
        p = unpkh(v2.y); a2 += w2 * p.x; a3 += w2 * p.y;
        p = unpkh(v3.x); a0 += w3 * p.x; a1 += w3 * p.y;
        p = unpkh(v3.y); a2 += w3 * p.x; a3 += w3 * p.y;
    }
    for (; j < e1; ++j) {
        int s = cs[j];
        float w = wc[(size_t)j * 3 + hd];
        uint2 v = hp[(size_t)s * 96 + tb];
        float2 p;
        p = unpkh(v.x); a0 += w * p.x; a1 += w * p.y;
        p = unpkh(v.y); a2 += w * p.x; a3 += w * p.y;
    }
    __shared__ float red[768];                    // br*384 + mt*192 + c
    int rb = br * 384 + mt * 192 + c;
    red[rb] = a0; red[rb + 1] = a1; red[rb + 2] = a2; red[rb + 3] = a3;
    __syncthreads();
    if (t < 128) {
        #pragma unroll
        for (int q = 0; q < 2; ++q) {
            int o = t + q * 128;                  // 0..255
            int obr = o >> 7, omt = (o >> 6) & 1, dd = o & 63;
            int base = obr * 384 + omt * 192;
            float tot = red[base + dd] + red[base + 64 + dd] + red[base + 128 + dd];
            const float* bias = omt ? blv : bmu;
            float v = tot * (1.f / 3.f) + bias[obr * 64 + dd];
            mt_gat[((size_t)(obr * 2 + omt) * NN + d) * 64 + dd] = v;
        }
    }
}

// ---------------- finalize: bias, z, 4-way max, outputs + split-fp16 z2 -------------
__global__ void k_finalize(const float* __restrict__ muv_gcn, const float* __restrict__ gcn_bmu,
                           const float* __restrict__ gcn_blv, const float* __restrict__ mt_gat,
                           const float* __restrict__ eps_gcn, const float* __restrict__ eps_gat,
                           float* __restrict__ mu_o, float* __restrict__ lv_o,
                           unsigned short* __restrict__ z2) {
    int i = blockIdx.x * 256 + threadIdx.x;       // NN*64
    int d = i >> 6, c = i & 63;
    const size_t NN64 = (size_t)NN * 64;
    float mu, lv, zm;
    {
        float m = muv_gcn[(size_t)d * 128 + c] + gcn_bmu[c];
        float l = muv_gcn[(size_t)d * 128 + 64 + c] + gcn_blv[c];
        float z = m + eps_gcn[i] * __expf(l);
        mu = m; lv = l; zm = z;
    }
    {
        float m = muv_gcn[NN64 * 2 + (size_t)d * 128 + c] + gcn_bmu[64 + c];
        float l = muv_gcn[NN64 * 2 + (size_t)d * 128 + 64 + c] + gcn_blv[64 + c];
        float z = m + eps_gcn[NN64 + i] * __expf(l);
        mu = fmaxf(mu, m); lv = fmaxf(lv, l); zm = fmaxf(zm, z);
    }
    #pragma unroll
    for (int br = 0; br < 2; ++br) {
        float m = mt_gat[(size_t)(br * 2 + 0) * NN64 + i];
        float l = mt_gat[(size_t)(br * 2 + 1) * NN64 + i];
        float z = m + eps_gat[(size_t)br * NN64 + i] * __expf(l);
        mu = fmaxf(mu, m); lv = fmaxf(lv, l); zm = fmaxf(zm, z);
    }
    mu_o[i] = mu;
    lv_o[i] = lv;
    unsigned short hh, ll;
    splith(zm, hh, ll);
    z2[(size_t)d * 128 + c] = hh;
    z2[(size_t)d * 128 + 64 + c] = ll;
}

extern "C" void kernel_launch(void* const* d_in, const int* in_sizes, int n_in,
                              void* d_out, int out_size, void* d_ws, size_t ws_size,
                              hipStream_t stream) {
    const float* x  = (const float*)d_in[0];
    const int*   ei = (const int*)d_in[1];
    const int E = in_sizes[1] / 2;
    const int E3 = E * 3;
    const int* src = ei;
    const int* dst = ei + E;

    const float* gcn_W1  = (const float*)d_in[2];
    const float* gcn_b1  = (const float*)d_in[3];
    const float* gcn_Wmu = (const float*)d_in[4];
    const float* gcn_bmu = (const float*)d_in[5];
    const float* gcn_Wlv = (const float*)d_in[6];
    const float* gcn_blv = (const float*)d_in[7];
    const float* gat_W1  = (const float*)d_in[8];
    const float* gat_as1 = (const float*)d_in[9];
    const float* gat_ad1 = (const float*)d_in[10];
    const float* gat_b1  = (const float*)d_in[11];
    const float* gat_Wmu = (const float*)d_in[12];
    const float* gat_asmu= (const float*)d_in[13];
    const float* gat_admu= (const float*)d_in[14];
    const float* gat_bmu = (const float*)d_in[15];
    const float* gat_Wlv = (const float*)d_in[16];
    const float* gat_aslv= (const float*)d_in[17];
    const float* gat_adlv= (const float*)d_in[18];
    const float* gat_blv = (const float*)d_in[19];
    const float* eps_gcn = (const float*)d_in[20];
    const float* eps_gat = (const float*)d_in[21];

    // ---- workspace carve ----
    char* p = (char*)d_ws;
    auto alloc = [&](size_t bytes) {
        void* r = (void*)p;
        p += (bytes + 255) & ~(size_t)255;
        return r;
    };
    int*   cnt     = (int*)alloc((size_t)NN * 4);
    int*   cursor  = (int*)alloc((size_t)NN * 4);       // contiguous after cnt
    int*   row_ptr = (int*)alloc((size_t)(NN + 1) * 4);
    int*   csr_src = (int*)alloc((size_t)E * 4);
    float* dinv    = (float*)alloc((size_t)NN * 4);
    float* as_n1   = (float*)alloc((size_t)2 * NN * 3 * 4);
    float* ad_n1   = (float*)alloc((size_t)2 * NN * 3 * 4);
    float* wself1  = (float*)alloc((size_t)2 * NN * 3 * 4);
    float* wcsr1   = (float*)alloc((size_t)2 * E3 * 4);
    float* as_n2   = (float*)alloc((size_t)4 * NN * 3 * 4);
    float* ad_n2   = (float*)alloc((size_t)4 * NN * 3 * 4);
    float* wself2  = (float*)alloc((size_t)4 * NN * 3 * 4);
    float* wcsr2   = (float*)alloc((size_t)4 * E3 * 4);
    unsigned short* x2h      = (unsigned short*)alloc((size_t)NN * 512 * 2);
    unsigned short* wt_all1  = (unsigned short*)alloc((size_t)1024 * 512 * 2);  // gcn rows 0..255, gat 256..1023
    unsigned short* wt_gcnmuv= (unsigned short*)alloc((size_t)2 * 128 * 128 * 2);
    unsigned short* wt_gatmuv= (unsigned short*)alloc((size_t)2 * 384 * 384 * 2);
    unsigned short* xw_all = (unsigned short*)alloc((size_t)NN * 1024 * 2);  // [gcn 256 | gat 768]
    unsigned short* hb   = (unsigned short*)alloc((size_t)NN * 256 * 2);
    unsigned short* hA   = (unsigned short*)alloc((size_t)NN * 256 * 2);
    float* muv_gcn = (float*)alloc((size_t)2 * NN * 128 * 4);
    unsigned short* h1s  = (unsigned short*)alloc((size_t)NN * 768 * 2);
    unsigned short* h2gb = (unsigned short*)alloc((size_t)2 * NN * 384 * 2);
    float* mt_gat  = (float*)alloc((size_t)4 * NN * 64 * 4);
    unsigned short* z2 = (unsigned short*)alloc((size_t)NN * 128 * 2);

    float* adj  = (float*)d_out;
    float* mu_o = adj + (size_t)NN * NN;
    float* lv_o = mu_o + (size_t)NN * 64;

    // ---- CSR build ----
    hipMemsetAsync(cnt, 0, (size_t)2 * NN * 4, stream);   // cnt + cursor
    k_count<<<(E + 255) / 256, 256, 0, stream>>>(dst, cnt, E);
    k_scan<<<1, 1024, 0, stream>>>(cnt, row_ptr, dinv);
    k_fill<<<(E + 255) / 256, 256, 0, stream>>>(src, dst, row_ptr, cursor, csr_src, E);

    // ---- precision prep (fp16) ----
    k_cvt_x<<<NN * 512 / 4 / 256, 256, 0, stream>>>(x, x2h);
    k_wT<<<dim3(16, 4, 2), 256, 0, stream>>>(gcn_W1, wt_all1, 512, 128, 0, 0, 128);
    k_wT<<<dim3(16, 12, 2), 256, 0, stream>>>(gat_W1, wt_all1, 512, 384, 0, 256, 384);
    k_wT2<<<dim3(4, 2, 4), 256, 0, stream>>>(gcn_Wmu, gcn_Wlv, wt_gcnmuv, 128, 64,
                                             (size_t)128 * 128, 64);
    k_wT2<<<dim3(12, 6, 4), 256, 0, stream>>>(gat_Wmu, gat_Wlv, wt_gatmuv, 384, 192,
                                              (size_t)384 * 384, 192);

    // ---- merged layer-1 GEMM: xw_all = fp16(x2h @ wt_all1)  (K=512, N=1024) ----
    k_gemm2<1, 2><<<dim3(64, 8, 1), 512, 0, stream>>>(x2h, 0, 512, wt_all1, 0, 512,
                                                      xw_all, 0, 1024, 512);

    // ---- GCN (both branches batched) ----
    k_gcn_a1<<<NN, 64, 0, stream>>>((const uint2*)xw_all, dinv, row_ptr, csr_src, gcn_b1,
                                    (uint2*)hb);
    k_gcn_a2<<<NN, 64, 0, stream>>>((const uint2*)hb, dinv, row_ptr, csr_src, (uint2*)hA);
    // g2: muv[z] = hA[z] @ wt_gcnmuv[z]  (K=128, N=128), fp32 out
    k_gemm2<1, 0><<<dim3(64, 1, 2), 512, 0, stream>>>(hA, 128, 256, wt_gcnmuv,
                                                      (size_t)128 * 128, 128,
                                                      muv_gcn, (size_t)NN * 128, 128, 128);

    // ---- GAT (both branches batched) ----
    k_gat_log1<<<dim3(NN, 1, 2), 192, 0, stream>>>((const unsigned int*)xw_all, gat_as1,
                                                   gat_ad1, as_n1, ad_n1);
    k_gat_attn<<<dim3(NN, 1, 2), 192, 0, stream>>>(as_n1, ad_n1, row_ptr, csr_src,
                                                   wcsr1, wself1, E3);
    k_gat_agg1<<<NN, 192, 0, stream>>>((const uint2*)xw_all, wcsr1, wself1, row_ptr, csr_src,
                                       gat_b1, (uint2*)h1s, E3);
    // G2: h2gb[z] = fp16(h1s[z] @ wt_gatmuv[z])  (K=384, N=384)
    k_gemm2<1, 2><<<dim3(64, 3, 2), 512, 0, stream>>>(h1s, 384, 768, wt_gatmuv,
                                                      (size_t)384 * 384, 384,
                                                      h2gb, (size_t)NN * 384, 384, 384);
    k_gat_log2<<<dim3(NN, 1, 4), 192, 0, stream>>>(h2gb, gat_asmu, gat_aslv, gat_admu,
                                                   gat_adlv, as_n2, ad_n2);
    k_gat_attn<<<dim3(NN, 1, 4), 192, 0, stream>>>(as_n2, ad_n2, row_ptr, csr_src,
                                                   wcsr2, wself2, E3);
    k_gat_agg2<<<NN, 192, 0, stream>>>((const uint2*)h2gb, wcsr2, wself2, row_ptr, csr_src,
                                       gat_bmu, gat_blv, mt_gat, E3);

    // ---- finalize + adjacency (fp16 hi/lo 2-term) ----
    k_finalize<<<NN * 64 / 256, 256, 0, stream>>>(muv_gcn, gcn_bmu, gcn_blv, mt_gat,
                                                  eps_gcn, eps_gat, mu_o, lv_o, z2);
    k_gemm2<2, 1><<<dim3(64, 64, 1), 512, 0, stream>>>(z2, 0, 128, z2, 0, 128,
                                                       adj, 0, NN, 64);
}